// Round 2
// baseline (6325.539 us; speedup 1.0000x reference)
//
#include <hip/hip_runtime.h>
#include <hip/hip_bf16.h>
#include <cstdint>
#include <cstddef>

constexpr int DIN = 64;
constexpr int DE  = 16;
constexpr int H   = 128;
constexpr int L   = 512;
constexpr int PD  = 1152;

// ---- typed load/store helpers (fp32 or bf16 big buffers)
__device__ __forceinline__ float ldv(const float* p) { return *p; }
__device__ __forceinline__ float ldv(const __hip_bfloat16* p) { return __bfloat162float(*p); }
__device__ __forceinline__ void stv(float* p, float v) { *p = v; }
__device__ __forceinline__ void stv(__hip_bfloat16* p, float v) { *p = __float2bfloat16(v); }

// ---------------------------------------------------------------- zero fill
__global__ void k_zero_i32(int* p, int n) {
  int i = blockIdx.x * 256 + threadIdx.x;
  if (i < n) p[i] = 0;
}
__global__ void k_zero_f32(float* p, int n) {
  int i = blockIdx.x * 256 + threadIdx.x;
  if (i < n) p[i] = 0.f;
}

// ---------------------------------------------------------------- CSR build
__global__ void k_deg(const int* __restrict__ dst, int* __restrict__ deg, int e) {
  int i = blockIdx.x * 256 + threadIdx.x;
  if (i < e) atomicAdd(&deg[dst[i]], 1);
}

__global__ void k_scan1(const int* __restrict__ deg, int* __restrict__ out,
                        int* __restrict__ bsum, int n) {
  __shared__ int tmp[512];
  int tid = threadIdx.x;
  int i = blockIdx.x * 512 + tid;
  int v = (i < n) ? deg[i] : 0;
  tmp[tid] = v; __syncthreads();
  for (int s = 1; s < 512; s <<= 1) {
    int t = (tid >= s) ? tmp[tid - s] : 0;
    __syncthreads();
    tmp[tid] += t;
    __syncthreads();
  }
  if (i < n) out[i] = tmp[tid] - v;            // exclusive within block
  if (tid == 511) bsum[blockIdx.x] = tmp[511]; // block total
}

__global__ void k_scan2(int* bsum, int nb) {  // nb <= 512
  __shared__ int tmp[512];
  int tid = threadIdx.x;
  int v = (tid < nb) ? bsum[tid] : 0;
  tmp[tid] = v; __syncthreads();
  for (int s = 1; s < 512; s <<= 1) {
    int t = (tid >= s) ? tmp[tid - s] : 0;
    __syncthreads();
    tmp[tid] += t;
    __syncthreads();
  }
  if (tid < nb) bsum[tid] = tmp[tid] - v;      // exclusive
}

__global__ void k_scan3(int* __restrict__ off, const int* __restrict__ bsum,
                        int* __restrict__ cursor, int n, int total) {
  int i = blockIdx.x * 512 + threadIdx.x;
  if (i < n) { int v = off[i] + bsum[blockIdx.x]; off[i] = v; cursor[i] = v; }
  if (i == 0) off[n] = total;
}

__global__ void k_fill(const int* __restrict__ dst, int* __restrict__ cursor,
                       int* __restrict__ eid, int e) {
  int i = blockIdx.x * 256 + threadIdx.x;
  if (i < e) { int slot = atomicAdd(&cursor[dst[i]], 1); eid[slot] = i; }
}

// ---------------------------------------------------------------- misc
// we[j] = sum_c We[j,c] * a_e[c]   (We is [DE,C])
__global__ void k_we(const float* __restrict__ We, const float* __restrict__ a_e,
                     float* __restrict__ we, int C) {
  int j = threadIdx.x;
  if (j < DE) {
    float acc = 0.f;
    for (int c = 0; c < C; ++c) acc += We[j * C + c] * a_e[c];
    we[j] = acc;
  }
}

// ---------------------------------------------------------------- GEMM: out[N,128] = in[N,K] @ W[K,128]
template <int K, typename TIN, typename TOUT>
__global__ void k_gemm128(const TIN* __restrict__ in, const float* __restrict__ W,
                          TOUT* __restrict__ out, int n) {
  __shared__ float lin[16][K];
  int tx = threadIdx.x & 127, ty = threadIdx.x >> 7;  // ty in {0,1}
  int row0 = blockIdx.x * 16;
  for (int idx = threadIdx.x; idx < 16 * K; idx += 256) {
    int r = idx / K, k = idx - r * K;
    int gr = row0 + r;
    lin[r][k] = (gr < n) ? ldv(&in[(size_t)gr * K + k]) : 0.f;
  }
  __syncthreads();
  float acc[8];
#pragma unroll
  for (int r = 0; r < 8; ++r) acc[r] = 0.f;
  for (int k = 0; k < K; ++k) {
    float w = W[k * 128 + tx];
#pragma unroll
    for (int r = 0; r < 8; ++r) acc[r] += lin[ty * 8 + r][k] * w;
  }
#pragma unroll
  for (int r = 0; r < 8; ++r) {
    int gr = row0 + ty * 8 + r;
    if (gr < n) stv(&out[(size_t)gr * 128 + tx], acc[r]);
  }
}

// s[n] = feat[n,:] . a_s ; d[n] = feat[n,:] . a_d   (C=128, one wave per node)
template <typename T>
__global__ void k_sd(const T* __restrict__ feat, const float* __restrict__ a_s,
                     const float* __restrict__ a_d, float* __restrict__ s,
                     float* __restrict__ d, int n) {
  int node = blockIdx.x * 4 + (threadIdx.x >> 6);
  int lane = threadIdx.x & 63;
  if (node >= n) return;
  const T* row = feat + (size_t)node * 128;
  float v0 = ldv(&row[lane]), v1 = ldv(&row[lane + 64]);
  float ps = v0 * a_s[lane] + v1 * a_s[lane + 64];
  float pd = v0 * a_d[lane] + v1 * a_d[lane + 64];
  for (int o = 32; o; o >>= 1) { ps += __shfl_down(ps, o); pd += __shfl_down(pd, o); }
  if (lane == 0) { s[node] = ps; d[node] = pd; }
}

// l[e] = leaky_relu(s[src] + d[dst] + eattr[e,:].we, 0.2)
__global__ void k_edge_l(const int* __restrict__ src, const int* __restrict__ dst,
                         const float* __restrict__ eattr, const float* __restrict__ we,
                         const float* __restrict__ s, const float* __restrict__ d,
                         float* __restrict__ lout, int e) {
  int i = blockIdx.x * 256 + threadIdx.x;
  if (i >= e) return;
  const float* ea = eattr + (size_t)i * DE;
  float acc = 0.f;
#pragma unroll
  for (int j = 0; j < DE; ++j) acc += ea[j] * we[j];
  float l = s[src[i]] + d[dst[i]] + acc;
  lout[i] = (l > 0.f) ? l : 0.2f * l;
}

// per-dst softmax over incoming edges + weighted gather; out[n,:] = bias + sum alpha*feat[src]
template <typename T>
__global__ void k_agg128(const int* __restrict__ off, const int* __restrict__ eid,
                         const int* __restrict__ src, const float* __restrict__ l,
                         const T* __restrict__ feat, const float* __restrict__ bias,
                         T* __restrict__ out, int n) {
  int node = blockIdx.x * 4 + (threadIdx.x >> 6);
  int lane = threadIdx.x & 63;
  if (node >= n) return;
  int e0 = off[node], e1 = off[node + 1];
  float m = -INFINITY;
  for (int i = e0 + lane; i < e1; i += 64) m = fmaxf(m, l[eid[i]]);
  for (int o = 32; o; o >>= 1) m = fmaxf(m, __shfl_xor(m, o));
  float den = 0.f;
  for (int i = e0 + lane; i < e1; i += 64) den += __expf(l[eid[i]] - m);
  for (int o = 32; o; o >>= 1) den += __shfl_xor(den, o);
  float inv = 1.0f / (den + 1e-16f);
  float a0 = 0.f, a1 = 0.f;
  for (int i = e0; i < e1; ++i) {
    int e = eid[i];
    float alpha = __expf(l[e] - m) * inv;
    const T* fr = feat + (size_t)src[e] * 128;
    a0 += alpha * ldv(&fr[lane]);
    a1 += alpha * ldv(&fr[lane + 64]);
  }
  stv(&out[(size_t)node * 128 + lane], a0 + bias[lane]);
  stv(&out[(size_t)node * 128 + lane + 64], a1 + bias[lane + 64]);
}

// gate feature: gfeat[n,0..4) = x[n,:] @ W[64,4]; also s,d scalars
__global__ void k_gfeat(const float* __restrict__ x, const float* __restrict__ W,
                        const float* __restrict__ a_s, const float* __restrict__ a_d,
                        float* __restrict__ gfeat, float* __restrict__ s,
                        float* __restrict__ d, int n) {
  int i = blockIdx.x * 256 + threadIdx.x;
  if (i >= n) return;
  const float* xr = x + (size_t)i * DIN;
  float acc[4] = {0.f, 0.f, 0.f, 0.f};
  for (int k = 0; k < DIN; ++k) {
    float xv = xr[k];
#pragma unroll
    for (int j = 0; j < 4; ++j) acc[j] += xv * W[k * 4 + j];
  }
  float ss = 0.f, dd = 0.f;
#pragma unroll
  for (int j = 0; j < 4; ++j) {
    gfeat[(size_t)i * 4 + j] = acc[j];
    ss += acc[j] * a_s[j];
    dd += acc[j] * a_d[j];
  }
  s[i] = ss; d[i] = dd;
}

// gate aggregation (C=4) + softmax over channels -> gates[n,0..4)
__global__ void k_agg4(const int* __restrict__ off, const int* __restrict__ eid,
                       const int* __restrict__ src, const float* __restrict__ l,
                       const float* __restrict__ gfeat, const float* __restrict__ bias,
                       float* __restrict__ gates, int n) {
  int node = blockIdx.x * 256 + threadIdx.x;
  if (node >= n) return;
  int e0 = off[node], e1 = off[node + 1];
  float m = -INFINITY;
  for (int i = e0; i < e1; ++i) m = fmaxf(m, l[eid[i]]);
  float den = 0.f;
  for (int i = e0; i < e1; ++i) den += __expf(l[eid[i]] - m);
  float inv = 1.f / (den + 1e-16f);
  float acc[4] = {0.f, 0.f, 0.f, 0.f};
  for (int i = e0; i < e1; ++i) {
    int e = eid[i];
    float a = __expf(l[e] - m) * inv;
    const float* fr = gfeat + (size_t)src[e] * 4;
#pragma unroll
    for (int j = 0; j < 4; ++j) acc[j] += a * fr[j];
  }
  float mm = -INFINITY;
#pragma unroll
  for (int j = 0; j < 4; ++j) { acc[j] += bias[j]; mm = fmaxf(mm, acc[j]); }
  float ssum = 0.f;
#pragma unroll
  for (int j = 0; j < 4; ++j) { acc[j] = __expf(acc[j] - mm); ssum += acc[j]; }
  float is = 1.f / ssum;
#pragma unroll
  for (int j = 0; j < 4; ++j) gates[(size_t)node * 4 + j] = acc[j] * is;
}

// per-channel sums / sumsq over x[n,128]
template <typename T>
__global__ void k_bnstats(const T* __restrict__ x, float* __restrict__ sums,
                          float* __restrict__ sumsq, int n) {
  __shared__ float s1[256], s2[256];
  int c = threadIdx.x & 127, half = threadIdx.x >> 7;
  float a = 0.f, b = 0.f;
  for (int r = blockIdx.x * 2 + half; r < n; r += gridDim.x * 2) {
    float v = ldv(&x[(size_t)r * 128 + c]);
    a += v; b += v * v;
  }
  s1[threadIdx.x] = a; s2[threadIdx.x] = b;
  __syncthreads();
  if (half == 0) {
    atomicAdd(&sums[c], s1[c] + s1[c + 128]);
    atomicAdd(&sumsq[c], s2[c] + s2[c + 128]);
  }
}

// y = leaky(bn(x), 0.01) in place
template <typename T>
__global__ void k_bnapply(T* __restrict__ x, const float* __restrict__ sums,
                          const float* __restrict__ sumsq, const float* __restrict__ g,
                          const float* __restrict__ b, int total, float invn) {
  int idx = blockIdx.x * 256 + threadIdx.x;
  if (idx >= total) return;
  int c = idx & 127;
  float mu = sums[c] * invn;
  float var = sumsq[c] * invn - mu * mu;
  float y = (ldv(&x[idx]) - mu) * rsqrtf(var + 1e-5f) * g[c] + b[c];
  stv(&x[idx], (y > 0.f) ? y : 0.01f * y);
}

// fused BN2 + leaky + gate-weight + segment-sum pooling (batch sorted; 1 block/graph)
template <typename T>
__global__ void k_poolexpert(const T* __restrict__ x, const float* __restrict__ sums,
                             const float* __restrict__ sumsq, const float* __restrict__ g,
                             const float* __restrict__ bb, const int* __restrict__ batch,
                             const float* __restrict__ gates0, int slot0,
                             const float* __restrict__ gates1, int slot1,
                             float* __restrict__ pooled0, float* __restrict__ pooled1,
                             int n, float invn) {
  int b = blockIdx.x, c = threadIdx.x;  // 128 threads
  int lo = 0, hi = n;
  while (lo < hi) { int m = (lo + hi) >> 1; if (batch[m] < b) lo = m + 1; else hi = m; }
  int start = lo;
  lo = start; hi = n;
  while (lo < hi) { int m = (lo + hi) >> 1; if (batch[m] < b + 1) lo = m + 1; else hi = m; }
  int end = lo;
  float mu = sums[c] * invn;
  float var = sumsq[c] * invn - mu * mu;
  float sc = rsqrtf(var + 1e-5f) * g[c];
  float sh = bb[c];
  float a0 = 0.f, a1 = 0.f;
  for (int r = start; r < end; ++r) {
    float y = (ldv(&x[(size_t)r * 128 + c]) - mu) * sc + sh;
    y = (y > 0.f) ? y : 0.01f * y;
    if (slot0 >= 0) a0 += gates0[(size_t)r * 4 + slot0] * y;
    if (slot1 >= 0) a1 += gates1[(size_t)r * 4 + slot1] * y;
  }
  if (slot0 >= 0) pooled0[(size_t)b * 128 + c] += a0;
  if (slot1 >= 0) pooled1[(size_t)b * 128 + c] += a1;
}

// K = pe @ Wk, V = pe @ Wv  (one block per l)
__global__ void k_kv(const float* __restrict__ pe, const float* __restrict__ Wk,
                     const float* __restrict__ Wv, float* __restrict__ Kout,
                     float* __restrict__ Vout) {
  __shared__ float per[PD];
  int l = blockIdx.x, c = threadIdx.x;
  for (int p = threadIdx.x; p < PD; p += 128) per[p] = pe[(size_t)l * PD + p];
  __syncthreads();
  float ak = 0.f, av = 0.f;
  for (int p = 0; p < PD; ++p) {
    float v = per[p];
    ak += v * Wk[p * 128 + c];
    av += v * Wv[p * 128 + c];
  }
  Kout[(size_t)l * 128 + c] = ak;
  Vout[(size_t)l * 128 + c] = av;
}

// out[row,:] = in[row,:Kdim] @ W[Kdim,128]
__global__ void k_rowgemm(const float* __restrict__ in, const float* __restrict__ W,
                          float* __restrict__ out, int Kdim) {
  __shared__ float rr[256];
  int row = blockIdx.x, c = threadIdx.x;
  for (int k = threadIdx.x; k < Kdim; k += 128) rr[k] = in[(size_t)row * Kdim + k];
  __syncthreads();
  float acc = 0.f;
  for (int k = 0; k < Kdim; ++k) acc += rr[k] * W[k * 128 + c];
  out[(size_t)row * 128 + c] = acc;
}

// cross-attention: per graph, softmax(Q.K^T/sqrt(H)) @ V
__global__ void k_attn(const float* __restrict__ Q, const float* __restrict__ Km,
                       const float* __restrict__ Vm, float* __restrict__ ctx) {
  __shared__ float q[128];
  __shared__ float sc[L];
  __shared__ float red[128];
  int b = blockIdx.x, t = threadIdx.x;
  q[t] = Q[(size_t)b * 128 + t];
  __syncthreads();
  float smax = -INFINITY;
  for (int j = 0; j < L / 128; ++j) {
    int l = t + j * 128;
    const float* kr = Km + (size_t)l * 128;
    float acc = 0.f;
    for (int k = 0; k < 128; ++k) acc += q[k] * kr[k];
    acc *= 0.08838834764831845f;  // 1/sqrt(128)
    sc[l] = acc;
    smax = fmaxf(smax, acc);
  }
  red[t] = smax; __syncthreads();
  for (int s = 64; s > 0; s >>= 1) { if (t < s) red[t] = fmaxf(red[t], red[t + s]); __syncthreads(); }
  float M = red[0]; __syncthreads();
  float ssum = 0.f;
  for (int j = 0; j < L / 128; ++j) {
    int l = t + j * 128;
    float e = __expf(sc[l] - M);
    sc[l] = e;
    ssum += e;
  }
  red[t] = ssum; __syncthreads();
  for (int s = 64; s > 0; s >>= 1) { if (t < s) red[t] += red[t + s]; __syncthreads(); }
  float inv = 1.f / red[0];
  __syncthreads();
  float acc = 0.f;
  for (int l = 0; l < L; ++l) acc += sc[l] * Vm[(size_t)l * 128 + t];
  ctx[(size_t)b * 128 + t] = acc * inv;
}

// hh = concat(pooled, ctx) @ Wh1 + bh1
__global__ void k_head1(const float* __restrict__ pooled, const float* __restrict__ ctx,
                        const float* __restrict__ Wh1, const float* __restrict__ bh1,
                        float* __restrict__ hh) {
  __shared__ float f[256];
  int b = blockIdx.x, c = threadIdx.x;
  f[c] = pooled[(size_t)b * 128 + c];
  f[c + 128] = ctx[(size_t)b * 128 + c];
  __syncthreads();
  float acc = bh1[c];
  for (int k = 0; k < 256; ++k) acc += f[k] * Wh1[k * 128 + c];
  hh[(size_t)b * 128 + c] = acc;
}

// bn + leaky + final dot with Wh2 -> out[b*2+t]
__global__ void k_head2(const float* __restrict__ hh, const float* __restrict__ sums,
                        const float* __restrict__ sumsq, const float* __restrict__ g,
                        const float* __restrict__ bbn, const float* __restrict__ Wh2,
                        const float* __restrict__ bh2, float* __restrict__ out, int t,
                        float invn) {
  __shared__ float red[2];
  int b = blockIdx.x, c = threadIdx.x;
  float mu = sums[c] * invn;
  float var = sumsq[c] * invn - mu * mu;
  float y = (hh[(size_t)b * 128 + c] - mu) * rsqrtf(var + 1e-5f) * g[c] + bbn[c];
  y = (y > 0.f) ? y : 0.01f * y;
  float p = y * Wh2[c];
  for (int o = 32; o; o >>= 1) p += __shfl_down(p, o);
  if ((threadIdx.x & 63) == 0) red[threadIdx.x >> 6] = p;
  __syncthreads();
  if (threadIdx.x == 0) out[(size_t)b * 2 + t] = red[0] + red[1] + bh2[0];
}

// ---------------------------------------------------------------- expert pipeline (templated on big-buffer dtype)
template <typename T>
static void run_experts(const float* x, const int* src, const int* dst, const float* eattr,
                        const int* batch, const float* eW1, const float* ea_s1,
                        const float* ea_d1, const float* eWe1, const float* ea_e1,
                        const float* eb1, const float* bn1_g, const float* bn1_b,
                        const float* eW2, const float* ea_s2, const float* ea_d2,
                        const float* eWe2, const float* ea_e2, const float* eb2,
                        const float* bn2_g, const float* bn2_b,
                        const int* off, const int* eid, float* s_arr, float* d_arr,
                        float* l_arr, float* webuf, float* sums,
                        const float* gates0, const float* gates1,
                        float* pooled0, float* pooled1,
                        T* featbuf, T* buf1, int n, int e, hipStream_t stream) {
  float invn = 1.0f / n;
  for (int i = 0; i < 6; ++i) {
    // layer 1 (DIN -> H)
    k_gemm128<DIN, float, T><<<(n + 15) / 16, 256, 0, stream>>>(x, eW1 + i * DIN * H,
                                                                featbuf, n);
    k_sd<T><<<(n + 3) / 4, 256, 0, stream>>>(featbuf, ea_s1 + i * H, ea_d1 + i * H,
                                             s_arr, d_arr, n);
    k_we<<<1, 64, 0, stream>>>(eWe1 + i * DE * H, ea_e1 + i * H, webuf, H);
    k_edge_l<<<(e + 255) / 256, 256, 0, stream>>>(src, dst, eattr, webuf, s_arr, d_arr,
                                                  l_arr, e);
    k_agg128<T><<<(n + 3) / 4, 256, 0, stream>>>(off, eid, src, l_arr, featbuf,
                                                 eb1 + i * H, buf1, n);
    k_zero_f32<<<1, 256, 0, stream>>>(sums, 256);
    k_bnstats<T><<<1024, 256, 0, stream>>>(buf1, sums, sums + 128, n);
    k_bnapply<T><<<(n * H + 255) / 256, 256, 0, stream>>>(buf1, sums, sums + 128,
                                                          bn1_g + i * H, bn1_b + i * H,
                                                          n * H, invn);
    // layer 2 (H -> H)
    k_gemm128<H, T, T><<<(n + 15) / 16, 256, 0, stream>>>(buf1, eW2 + i * H * H,
                                                          featbuf, n);
    k_sd<T><<<(n + 3) / 4, 256, 0, stream>>>(featbuf, ea_s2 + i * H, ea_d2 + i * H,
                                             s_arr, d_arr, n);
    k_we<<<1, 64, 0, stream>>>(eWe2 + i * DE * H, ea_e2 + i * H, webuf, H);
    k_edge_l<<<(e + 255) / 256, 256, 0, stream>>>(src, dst, eattr, webuf, s_arr, d_arr,
                                                  l_arr, e);
    k_agg128<T><<<(n + 3) / 4, 256, 0, stream>>>(off, eid, src, l_arr, featbuf,
                                                 eb2 + i * H, buf1, n);
    k_zero_f32<<<1, 256, 0, stream>>>(sums, 256);
    k_bnstats<T><<<1024, 256, 0, stream>>>(buf1, sums, sums + 128, n);
    int s0 = (i < 4) ? i : -1;                     // task0: experts 0,1,2,3
    int s1 = (i < 2) ? i : (i >= 4 ? i - 2 : -1);  // task1: experts 0,1,4,5
    int nblk = 4096;  // B graphs
    k_poolexpert<T><<<nblk, 128, 0, stream>>>(buf1, sums, sums + 128, bn2_g + i * H,
                                              bn2_b + i * H, batch, gates0, s0, gates1,
                                              s1, pooled0, pooled1, n, invn);
  }
}

extern "C" void kernel_launch(void* const* d_in, const int* in_sizes, int n_in,
                              void* d_out, int out_size, void* d_ws, size_t ws_size,
                              hipStream_t stream) {
  (void)n_in;
  const float* x     = (const float*)d_in[0];
  const int*   eidx  = (const int*)d_in[1];
  const float* eattr = (const float*)d_in[2];
  const int*   batch = (const int*)d_in[3];
  const float* eW1   = (const float*)d_in[4];
  const float* ea_s1 = (const float*)d_in[5];
  const float* ea_d1 = (const float*)d_in[6];
  const float* eWe1  = (const float*)d_in[7];
  const float* ea_e1 = (const float*)d_in[8];
  const float* eb1   = (const float*)d_in[9];
  const float* bn1_g = (const float*)d_in[10];
  const float* bn1_b = (const float*)d_in[11];
  const float* eW2   = (const float*)d_in[12];
  const float* ea_s2 = (const float*)d_in[13];
  const float* ea_d2 = (const float*)d_in[14];
  const float* eWe2  = (const float*)d_in[15];
  const float* ea_e2 = (const float*)d_in[16];
  const float* eb2   = (const float*)d_in[17];
  const float* bn2_g = (const float*)d_in[18];
  const float* bn2_b = (const float*)d_in[19];
  const float* gW    = (const float*)d_in[20];
  const float* ga_s  = (const float*)d_in[21];
  const float* ga_d  = (const float*)d_in[22];
  const float* gWe   = (const float*)d_in[23];
  const float* ga_e  = (const float*)d_in[24];
  const float* gb    = (const float*)d_in[25];
  const float* Wq    = (const float*)d_in[26];
  const float* Wk    = (const float*)d_in[27];
  const float* Wv    = (const float*)d_in[28];
  const float* pe    = (const float*)d_in[29];
  const float* Wh1   = (const float*)d_in[30];
  const float* bh1   = (const float*)d_in[31];
  const float* hbn_g = (const float*)d_in[32];
  const float* hbn_b = (const float*)d_in[33];
  const float* Wh2   = (const float*)d_in[34];
  const float* bh2   = (const float*)d_in[35];
  float* out = (float*)d_out;

  const int n = in_sizes[0] / DIN;   // 200000
  const int e = in_sizes[1] / 2;     // 800000
  const int nb_graphs = out_size / 2; // 4096
  const int* src = eidx;
  const int* dst = eidx + e;

  char* p = (char*)d_ws;
  auto carve = [&](size_t bytes) {
    void* r = (void*)p;
    p += (bytes + 255) & ~(size_t)255;
    return r;
  };
  int* deg       = (int*)carve((size_t)n * 4);
  int* off       = (int*)carve(((size_t)n + 1) * 4);
  int* cursor    = (int*)carve((size_t)n * 4);
  int* eid       = (int*)carve((size_t)e * 4);
  int* bsum      = (int*)carve(4096);
  float* s_arr   = (float*)carve((size_t)n * 4);
  float* d_arr   = (float*)carve((size_t)n * 4);
  float* l_arr   = (float*)carve((size_t)e * 4);
  float* webuf   = (float*)carve(256);
  float* sums    = (float*)carve(256 * 4);
  float* gates0  = (float*)carve((size_t)n * 16);
  float* gates1  = (float*)carve((size_t)n * 16);
  float* gfeat   = (float*)carve((size_t)n * 16);
  float* pooled0 = (float*)carve((size_t)nb_graphs * H * 4);
  float* pooled1 = (float*)carve((size_t)nb_graphs * H * 4);
  float* Kbuf    = (float*)carve((size_t)L * H * 4);
  float* Vbuf    = (float*)carve((size_t)L * H * 4);
  float* Qbuf    = (float*)carve((size_t)nb_graphs * H * 4);
  float* ctxb    = (float*)carve((size_t)nb_graphs * H * 4);
  float* hhb     = (float*)carve((size_t)nb_graphs * H * 4);

  // big buffers: fp32 if workspace allows, else bf16
  size_t used = (size_t)(p - (char*)d_ws);
  size_t remain = (ws_size > used) ? ws_size - used : 0;
  size_t need_fp32 = 2 * (((size_t)n * H * 4 + 255) & ~(size_t)255);
  bool fp32path = remain >= need_fp32;

  // ---- CSR by dst (reused by all 14 GAT convs)
  k_zero_i32<<<(n + 255) / 256, 256, 0, stream>>>(deg, n);
  k_deg<<<(e + 255) / 256, 256, 0, stream>>>(dst, deg, e);
  int nsb = (n + 511) / 512;
  k_scan1<<<nsb, 512, 0, stream>>>(deg, off, bsum, n);
  k_scan2<<<1, 512, 0, stream>>>(bsum, nsb);
  k_scan3<<<nsb, 512, 0, stream>>>(off, bsum, cursor, n, e);
  k_fill<<<(e + 255) / 256, 256, 0, stream>>>(dst, cursor, eid, e);

  // ---- gates (2 tasks)
  for (int t = 0; t < 2; ++t) {
    float* gates = t ? gates1 : gates0;
    k_gfeat<<<(n + 255) / 256, 256, 0, stream>>>(x, gW + t * DIN * 4, ga_s + t * 4,
                                                 ga_d + t * 4, gfeat, s_arr, d_arr, n);
    k_we<<<1, 64, 0, stream>>>(gWe + t * DE * 4, ga_e + t * 4, webuf, 4);
    k_edge_l<<<(e + 255) / 256, 256, 0, stream>>>(src, dst, eattr, webuf, s_arr, d_arr,
                                                  l_arr, e);
    k_agg4<<<(n + 255) / 256, 256, 0, stream>>>(off, eid, src, l_arr, gfeat, gb + t * 4,
                                                gates, n);
  }

  // ---- zero pooled accumulators
  k_zero_f32<<<(nb_graphs * H + 255) / 256, 256, 0, stream>>>(pooled0, nb_graphs * H);
  k_zero_f32<<<(nb_graphs * H + 255) / 256, 256, 0, stream>>>(pooled1, nb_graphs * H);

  // ---- 6 experts with fused BN2+gate+pool epilogue
  if (fp32path) {
    float* featbuf = (float*)carve((size_t)n * H * 4);
    float* buf1    = (float*)carve((size_t)n * H * 4);
    run_experts<float>(x, src, dst, eattr, batch, eW1, ea_s1, ea_d1, eWe1, ea_e1, eb1,
                       bn1_g, bn1_b, eW2, ea_s2, ea_d2, eWe2, ea_e2, eb2, bn2_g, bn2_b,
                       off, eid, s_arr, d_arr, l_arr, webuf, sums, gates0, gates1,
                       pooled0, pooled1, featbuf, buf1, n, e, stream);
  } else {
    __hip_bfloat16* featbuf = (__hip_bfloat16*)carve((size_t)n * H * 2);
    __hip_bfloat16* buf1    = (__hip_bfloat16*)carve((size_t)n * H * 2);
    run_experts<__hip_bfloat16>(x, src, dst, eattr, batch, eW1, ea_s1, ea_d1, eWe1,
                                ea_e1, eb1, bn1_g, bn1_b, eW2, ea_s2, ea_d2, eWe2,
                                ea_e2, eb2, bn2_g, bn2_b, off, eid, s_arr, d_arr, l_arr,
                                webuf, sums, gates0, gates1, pooled0, pooled1, featbuf,
                                buf1, n, e, stream);
  }

  // ---- heads
  for (int t = 0; t < 2; ++t) {
    const float* pooled = t ? pooled1 : pooled0;
    k_kv<<<L, 128, 0, stream>>>(pe + (size_t)t * L * PD, Wk + t * PD * H, Wv + t * PD * H,
                                Kbuf, Vbuf);
    k_rowgemm<<<nb_graphs, 128, 0, stream>>>(pooled, Wq + t * H * H, Qbuf, H);
    k_attn<<<nb_graphs, 128, 0, stream>>>(Qbuf, Kbuf, Vbuf, ctxb);
    k_head1<<<nb_graphs, 128, 0, stream>>>(pooled, ctxb, Wh1 + t * 2 * H * H, bh1 + t * H,
                                           hhb);
    k_zero_f32<<<1, 256, 0, stream>>>(sums, 256);
    k_bnstats<float><<<256, 256, 0, stream>>>(hhb, sums, sums + 128, nb_graphs);
    k_head2<<<nb_graphs, 128, 0, stream>>>(hhb, sums, sums + 128, hbn_g + t * H,
                                           hbn_b + t * H, Wh2 + t * H, bh2 + t, out, t,
                                           1.0f / nb_graphs);
  }
}

// Round 3
// 4998.264 us; speedup vs baseline: 1.2655x; 1.2655x over previous
//
#include <hip/hip_runtime.h>
#include <hip/hip_bf16.h>
#include <cstdint>
#include <cstddef>
#include <type_traits>

constexpr int DIN = 64;
constexpr int DE  = 16;
constexpr int H   = 128;
constexpr int L   = 512;
constexpr int PD  = 1152;

using bf16 = __hip_bfloat16;

// ---- bf16 pack/unpack helpers (bf16x2 in a uint) ----
__device__ __forceinline__ float bflo(unsigned u) { return __uint_as_float(u << 16); }
__device__ __forceinline__ float bfhi(unsigned u) { return __uint_as_float(u & 0xffff0000u); }
__device__ __forceinline__ unsigned short f2b(float f) {
  bf16 h = __float2bfloat16(f);
  return *reinterpret_cast<unsigned short*>(&h);
}
__device__ __forceinline__ unsigned pack2(float a, float b) {
  return (unsigned)f2b(a) | ((unsigned)f2b(b) << 16);
}

// ---------------------------------------------------------------- zero fill
__global__ void k_zero_i32(int* p, int n) {
  int i = blockIdx.x * 256 + threadIdx.x;
  if (i < n) p[i] = 0;
}
__global__ void k_zero_f32(float* p, int n) {
  int i = blockIdx.x * 256 + threadIdx.x;
  if (i < n) p[i] = 0.f;
}

// ---------------------------------------------------------------- CSR build
__global__ void k_deg(const int* __restrict__ dst, int* __restrict__ deg, int e) {
  int i = blockIdx.x * 256 + threadIdx.x;
  if (i < e) atomicAdd(&deg[dst[i]], 1);
}

__global__ void k_scan1(const int* __restrict__ deg, int* __restrict__ out,
                        int* __restrict__ bsum, int n) {
  __shared__ int tmp[512];
  int tid = threadIdx.x;
  int i = blockIdx.x * 512 + tid;
  int v = (i < n) ? deg[i] : 0;
  tmp[tid] = v; __syncthreads();
  for (int s = 1; s < 512; s <<= 1) {
    int t = (tid >= s) ? tmp[tid - s] : 0;
    __syncthreads();
    tmp[tid] += t;
    __syncthreads();
  }
  if (i < n) out[i] = tmp[tid] - v;
  if (tid == 511) bsum[blockIdx.x] = tmp[511];
}

__global__ void k_scan2(int* bsum, int nb) {  // nb <= 512
  __shared__ int tmp[512];
  int tid = threadIdx.x;
  int v = (tid < nb) ? bsum[tid] : 0;
  tmp[tid] = v; __syncthreads();
  for (int s = 1; s < 512; s <<= 1) {
    int t = (tid >= s) ? tmp[tid - s] : 0;
    __syncthreads();
    tmp[tid] += t;
    __syncthreads();
  }
  if (tid < nb) bsum[tid] = tmp[tid] - v;
}

__global__ void k_scan3(int* __restrict__ off, const int* __restrict__ bsum,
                        int* __restrict__ cursor, int n, int total) {
  int i = blockIdx.x * 512 + threadIdx.x;
  if (i < n) { int v = off[i] + bsum[blockIdx.x]; off[i] = v; cursor[i] = v; }
  if (i == 0) off[n] = total;
}

__global__ void k_fill(const int* __restrict__ dst, int* __restrict__ cursor,
                       int* __restrict__ eid, int e) {
  int i = blockIdx.x * 256 + threadIdx.x;
  if (i < e) { int slot = atomicAdd(&cursor[dst[i]], 1); eid[slot] = i; }
}

// ---------------------------------------------------------------- weall: all 14 conv edge-weight vectors [14][16]
// conv c: 0,1 = gates; 2..7 = expert layer1; 8..13 = expert layer2
__global__ void k_weall(const float* __restrict__ gWe, const float* __restrict__ ga_e,
                        const float* __restrict__ eWe1, const float* __restrict__ ea_e1,
                        const float* __restrict__ eWe2, const float* __restrict__ ea_e2,
                        float* __restrict__ weall) {
  int tid = threadIdx.x;
  if (tid >= 14 * 16) return;
  int c = tid >> 4, j = tid & 15;
  float acc = 0.f;
  if (c < 2) {
    for (int k = 0; k < 4; ++k) acc += gWe[(c * 16 + j) * 4 + k] * ga_e[c * 4 + k];
  } else if (c < 8) {
    int i = c - 2;
    for (int k = 0; k < 128; ++k) acc += eWe1[(i * 16 + j) * 128 + k] * ea_e1[i * 128 + k];
  } else {
    int i = c - 8;
    for (int k = 0; k < 128; ++k) acc += eWe2[(i * 16 + j) * 128 + k] * ea_e2[i * 128 + k];
  }
  weall[c * 16 + j] = acc;
}

// ---------------------------------------------------------------- CSR prep: src/dst in CSR order + all 14 edots
__global__ void k_csrprep(const int* __restrict__ eid, const int* __restrict__ src,
                          const int* __restrict__ dst, const float* __restrict__ eattr,
                          const float* __restrict__ weall, int* __restrict__ src_csr,
                          int* __restrict__ dst_csr, float* __restrict__ edots, int e) {
  __shared__ float w[14 * 16];
  if (threadIdx.x < 14 * 16) w[threadIdx.x] = weall[threadIdx.x];
  __syncthreads();
  int i = blockIdx.x * 256 + threadIdx.x;
  if (i >= e) return;
  int ed = eid[i];
  src_csr[i] = src[ed];
  dst_csr[i] = dst[ed];
  float ea[16];
  const float4* ep = (const float4*)(eattr + (size_t)ed * 16);
#pragma unroll
  for (int q = 0; q < 4; ++q) {
    float4 v = ep[q];
    ea[q * 4] = v.x; ea[q * 4 + 1] = v.y; ea[q * 4 + 2] = v.z; ea[q * 4 + 3] = v.w;
  }
#pragma unroll
  for (int c = 0; c < 14; ++c) {
    float acc = 0.f;
#pragma unroll
    for (int j = 0; j < 16; ++j) acc += ea[j] * w[c * 16 + j];
    edots[(size_t)c * e + i] = acc;
  }
}

// ---------------------------------------------------------------- GEMM: out[N,128](bf16) = in[N,K] @ W[K,128]
template <int K, typename TIN>
__global__ void k_gemm128(const TIN* __restrict__ in, const float* __restrict__ W,
                          bf16* __restrict__ out, int n) {
  __shared__ float lin[16][K];
  int tx = threadIdx.x & 127, ty = threadIdx.x >> 7;  // ty in {0,1}
  int row0 = blockIdx.x * 16;
  if constexpr (std::is_same<TIN, bf16>::value) {
    const unsigned* ip = (const unsigned*)in;
    constexpr int PR = K / 2;  // pairs per row
    for (int idx = threadIdx.x; idx < 16 * PR; idx += 256) {
      int r = idx / PR, p2 = idx - r * PR;
      int gr = row0 + r;
      unsigned u = (gr < n) ? ip[(size_t)gr * PR + p2] : 0u;
      lin[r][2 * p2] = bflo(u);
      lin[r][2 * p2 + 1] = bfhi(u);
    }
  } else {
    for (int idx = threadIdx.x; idx < 16 * K; idx += 256) {
      int r = idx / K, k = idx - r * K;
      int gr = row0 + r;
      lin[r][k] = (gr < n) ? in[(size_t)gr * K + k] : 0.f;
    }
  }
  __syncthreads();
  float acc[8];
#pragma unroll
  for (int r = 0; r < 8; ++r) acc[r] = 0.f;
  for (int k = 0; k < K; ++k) {
    float w = W[k * 128 + tx];
#pragma unroll
    for (int r = 0; r < 8; ++r) acc[r] += lin[ty * 8 + r][k] * w;
  }
#pragma unroll
  for (int r = 0; r < 8; ++r) {
    int gr = row0 + ty * 8 + r;
    if (gr < n) out[(size_t)gr * 128 + tx] = __float2bfloat16(acc[r]);
  }
}

// ---------------------------------------------------------------- s/d per node (bf16 feat, one wave per node)
__global__ void k_sd(const bf16* __restrict__ feat, const float* __restrict__ a_s,
                     const float* __restrict__ a_d, float* __restrict__ s,
                     float* __restrict__ d, int n) {
  int node = blockIdx.x * 4 + (threadIdx.x >> 6);
  int lane = threadIdx.x & 63;
  if (node >= n) return;
  const unsigned* rp = (const unsigned*)(feat + (size_t)node * 128);
  unsigned u = rp[lane];  // channels 2*lane, 2*lane+1
  float v0 = bflo(u), v1 = bfhi(u);
  float2 as = ((const float2*)a_s)[lane];
  float2 ad = ((const float2*)a_d)[lane];
  float ps = v0 * as.x + v1 * as.y;
  float pd = v0 * ad.x + v1 * ad.y;
  for (int o = 32; o; o >>= 1) { ps += __shfl_xor(ps, o); pd += __shfl_xor(pd, o); }
  if (lane == 0) { s[node] = ps; d[node] = pd; }
}

// ---------------------------------------------------------------- edge logits in CSR order
__global__ void k_edge_l(const int* __restrict__ src_csr, const int* __restrict__ dst_csr,
                         const float* __restrict__ edot, const float* __restrict__ s,
                         const float* __restrict__ d, float* __restrict__ lcsr, int e) {
  int i = blockIdx.x * 256 + threadIdx.x;
  if (i >= e) return;
  float l = s[src_csr[i]] + d[dst_csr[i]] + edot[i];
  lcsr[i] = (l > 0.f) ? l : 0.2f * l;
}

// ---------------------------------------------------------------- agg: softmax over incoming + gather (32 lanes/node)
__global__ void k_agg128(const int* __restrict__ off, const int* __restrict__ src_csr,
                         const float* __restrict__ lcsr, const bf16* __restrict__ feat,
                         const float* __restrict__ bias, bf16* __restrict__ out, int n) {
  int node = blockIdx.x * 8 + (threadIdx.x >> 5);
  int lane = threadIdx.x & 31;
  if (node >= n) return;
  int e0 = off[node], e1 = off[node + 1];
  float m = -INFINITY;
  for (int i = e0 + lane; i < e1; i += 32) m = fmaxf(m, lcsr[i]);
  for (int o = 16; o; o >>= 1) m = fmaxf(m, __shfl_xor(m, o));
  float den = 0.f;
  for (int i = e0 + lane; i < e1; i += 32) den += __expf(lcsr[i] - m);
  for (int o = 16; o; o >>= 1) den += __shfl_xor(den, o);
  float inv = 1.0f / (den + 1e-16f);
  float4 acc = {0.f, 0.f, 0.f, 0.f};
  for (int i = e0; i < e1; ++i) {
    float alpha = __expf(lcsr[i] - m) * inv;
    const uint2* fr = (const uint2*)(feat + (size_t)src_csr[i] * 128);
    uint2 u = fr[lane];  // channels 4*lane .. 4*lane+3
    acc.x += alpha * bflo(u.x);
    acc.y += alpha * bfhi(u.x);
    acc.z += alpha * bflo(u.y);
    acc.w += alpha * bfhi(u.y);
  }
  float4 b4 = ((const float4*)bias)[lane];
  uint2 o2;
  o2.x = pack2(acc.x + b4.x, acc.y + b4.y);
  o2.y = pack2(acc.z + b4.z, acc.w + b4.w);
  ((uint2*)(out + (size_t)node * 128))[lane] = o2;
}

// ---------------------------------------------------------------- gate feature + s/d
__global__ void k_gfeat(const float* __restrict__ x, const float* __restrict__ W,
                        const float* __restrict__ a_s, const float* __restrict__ a_d,
                        float* __restrict__ gfeat, float* __restrict__ s,
                        float* __restrict__ d, int n) {
  int i = blockIdx.x * 256 + threadIdx.x;
  if (i >= n) return;
  const float* xr = x + (size_t)i * DIN;
  float acc[4] = {0.f, 0.f, 0.f, 0.f};
  for (int k = 0; k < DIN; ++k) {
    float xv = xr[k];
#pragma unroll
    for (int j = 0; j < 4; ++j) acc[j] += xv * W[k * 4 + j];
  }
  float ss = 0.f, dd = 0.f;
#pragma unroll
  for (int j = 0; j < 4; ++j) {
    gfeat[(size_t)i * 4 + j] = acc[j];
    ss += acc[j] * a_s[j];
    dd += acc[j] * a_d[j];
  }
  s[i] = ss; d[i] = dd;
}

// ---------------------------------------------------------------- gate aggregation + channel softmax
__global__ void k_agg4(const int* __restrict__ off, const int* __restrict__ src_csr,
                       const float* __restrict__ lcsr, const float* __restrict__ gfeat,
                       const float* __restrict__ bias, float* __restrict__ gates, int n) {
  int node = blockIdx.x * 256 + threadIdx.x;
  if (node >= n) return;
  int e0 = off[node], e1 = off[node + 1];
  float m = -INFINITY;
  for (int i = e0; i < e1; ++i) m = fmaxf(m, lcsr[i]);
  float den = 0.f;
  for (int i = e0; i < e1; ++i) den += __expf(lcsr[i] - m);
  float inv = 1.f / (den + 1e-16f);
  float4 acc = {0.f, 0.f, 0.f, 0.f};
  for (int i = e0; i < e1; ++i) {
    float a = __expf(lcsr[i] - m) * inv;
    float4 fr = *((const float4*)(gfeat + (size_t)src_csr[i] * 4));
    acc.x += a * fr.x; acc.y += a * fr.y; acc.z += a * fr.z; acc.w += a * fr.w;
  }
  float b0 = bias[0], b1 = bias[1], b2 = bias[2], b3 = bias[3];
  acc.x += b0; acc.y += b1; acc.z += b2; acc.w += b3;
  float mm = fmaxf(fmaxf(acc.x, acc.y), fmaxf(acc.z, acc.w));
  float e0s = __expf(acc.x - mm), e1s = __expf(acc.y - mm);
  float e2s = __expf(acc.z - mm), e3s = __expf(acc.w - mm);
  float is = 1.f / (e0s + e1s + e2s + e3s);
  float4 g4 = {e0s * is, e1s * is, e2s * is, e3s * is};
  *((float4*)(gates + (size_t)node * 4)) = g4;
}

// ---------------------------------------------------------------- BN stats (bf16, vectorized)
__global__ void k_bnstats_bf(const bf16* __restrict__ x, float* __restrict__ sums,
                             float* __restrict__ sumsq, int n) {
  __shared__ float4 sA[256], sB[256];
  int qc = threadIdx.x & 31;    // channel quad 0..31 -> channels 4qc..4qc+3
  int rg = threadIdx.x >> 5;    // row group 0..7
  float4 a = {0, 0, 0, 0}, b = {0, 0, 0, 0};
  for (int r = blockIdx.x * 8 + rg; r < n; r += gridDim.x * 8) {
    uint2 u = ((const uint2*)(x + (size_t)r * 128))[qc];
    float f0 = bflo(u.x), f1 = bfhi(u.x), f2 = bflo(u.y), f3 = bfhi(u.y);
    a.x += f0; a.y += f1; a.z += f2; a.w += f3;
    b.x += f0 * f0; b.y += f1 * f1; b.z += f2 * f2; b.w += f3 * f3;
  }
  sA[threadIdx.x] = a; sB[threadIdx.x] = b;
  __syncthreads();
  if (rg == 0) {
#pragma unroll
    for (int g = 1; g < 8; ++g) {
      float4 ta = sA[g * 32 + qc], tb = sB[g * 32 + qc];
      a.x += ta.x; a.y += ta.y; a.z += ta.z; a.w += ta.w;
      b.x += tb.x; b.y += tb.y; b.z += tb.z; b.w += tb.w;
    }
    int c = qc * 4;
    atomicAdd(&sums[c], a.x); atomicAdd(&sums[c + 1], a.y);
    atomicAdd(&sums[c + 2], a.z); atomicAdd(&sums[c + 3], a.w);
    atomicAdd(&sumsq[c], b.x); atomicAdd(&sumsq[c + 1], b.y);
    atomicAdd(&sumsq[c + 2], b.z); atomicAdd(&sumsq[c + 3], b.w);
  }
}

// BN stats fp32 (head path, [n,128])
__global__ void k_bnstats_f32(const float* __restrict__ x, float* __restrict__ sums,
                              float* __restrict__ sumsq, int n) {
  __shared__ float s1[256], s2[256];
  int c = threadIdx.x & 127, half = threadIdx.x >> 7;
  float a = 0.f, b = 0.f;
  for (int r = blockIdx.x * 2 + half; r < n; r += gridDim.x * 2) {
    float v = x[(size_t)r * 128 + c];
    a += v; b += v * v;
  }
  s1[threadIdx.x] = a; s2[threadIdx.x] = b;
  __syncthreads();
  if (half == 0) {
    atomicAdd(&sums[c], s1[c] + s1[c + 128]);
    atomicAdd(&sumsq[c], s2[c] + s2[c + 128]);
  }
}

// ---------------------------------------------------------------- BN apply + leaky (bf16 in place)
__global__ void k_bnapply_bf(bf16* __restrict__ x, const float* __restrict__ sums,
                             const float* __restrict__ sumsq, const float* __restrict__ g,
                             const float* __restrict__ b, int nquads, float invn) {
  int idx = blockIdx.x * 256 + threadIdx.x;
  if (idx >= nquads) return;
  int c = (idx & 31) * 4;
  uint2 u = ((uint2*)x)[idx];
  float y[4] = {bflo(u.x), bfhi(u.x), bflo(u.y), bfhi(u.y)};
#pragma unroll
  for (int k = 0; k < 4; ++k) {
    float mu = sums[c + k] * invn;
    float var = sumsq[c + k] * invn - mu * mu;
    float v = (y[k] - mu) * rsqrtf(var + 1e-5f) * g[c + k] + b[c + k];
    y[k] = (v > 0.f) ? v : 0.01f * v;
  }
  uint2 o;
  o.x = pack2(y[0], y[1]);
  o.y = pack2(y[2], y[3]);
  ((uint2*)x)[idx] = o;
}

// ---------------------------------------------------------------- fused BN2+leaky+gate+pool (bf16, 64 thr/graph)
__global__ void k_poolexpert(const bf16* __restrict__ x, const float* __restrict__ sums,
                             const float* __restrict__ sumsq, const float* __restrict__ g,
                             const float* __restrict__ bb, const int* __restrict__ batch,
                             const float* __restrict__ gates0, int slot0,
                             const float* __restrict__ gates1, int slot1,
                             float* __restrict__ pooled0, float* __restrict__ pooled1,
                             int n, float invn) {
  int b = blockIdx.x, t = threadIdx.x;  // 64 threads, channels 2t,2t+1
  int lo = 0, hi = n;
  while (lo < hi) { int m = (lo + hi) >> 1; if (batch[m] < b) lo = m + 1; else hi = m; }
  int start = lo;
  lo = start; hi = n;
  while (lo < hi) { int m = (lo + hi) >> 1; if (batch[m] < b + 1) lo = m + 1; else hi = m; }
  int end = lo;
  int c0 = 2 * t, c1 = 2 * t + 1;
  float mu0 = sums[c0] * invn, mu1 = sums[c1] * invn;
  float sc0 = rsqrtf(sumsq[c0] * invn - mu0 * mu0 + 1e-5f) * g[c0];
  float sc1 = rsqrtf(sumsq[c1] * invn - mu1 * mu1 + 1e-5f) * g[c1];
  float sh0 = bb[c0], sh1 = bb[c1];
  float a00 = 0.f, a01 = 0.f, a10 = 0.f, a11 = 0.f;
  for (int r = start; r < end; ++r) {
    unsigned u = ((const unsigned*)(x + (size_t)r * 128))[t];
    float y0 = (bflo(u) - mu0) * sc0 + sh0;
    float y1 = (bfhi(u) - mu1) * sc1 + sh1;
    y0 = (y0 > 0.f) ? y0 : 0.01f * y0;
    y1 = (y1 > 0.f) ? y1 : 0.01f * y1;
    if (slot0 >= 0) {
      float gw = gates0[(size_t)r * 4 + slot0];
      a00 += gw * y0; a01 += gw * y1;
    }
    if (slot1 >= 0) {
      float gw = gates1[(size_t)r * 4 + slot1];
      a10 += gw * y0; a11 += gw * y1;
    }
  }
  if (slot0 >= 0) {
    pooled0[(size_t)b * 128 + c0] += a00;
    pooled0[(size_t)b * 128 + c1] += a01;
  }
  if (slot1 >= 0) {
    pooled1[(size_t)b * 128 + c0] += a10;
    pooled1[(size_t)b * 128 + c1] += a11;
  }
}

// ---------------------------------------------------------------- K^T = (pe@Wk)^T [128][L], V = pe@Wv [L][128]
__global__ void k_kv(const float* __restrict__ pe, const float* __restrict__ Wk,
                     const float* __restrict__ Wv, float* __restrict__ Kt,
                     float* __restrict__ Vout) {
  __shared__ float per[PD];
  int l = blockIdx.x, c = threadIdx.x;
  for (int p = threadIdx.x; p < PD; p += 128) per[p] = pe[(size_t)l * PD + p];
  __syncthreads();
  float ak = 0.f, av = 0.f;
  for (int p = 0; p < PD; ++p) {
    float v = per[p];
    ak += v * Wk[p * 128 + c];
    av += v * Wv[p * 128 + c];
  }
  Kt[(size_t)c * L + l] = ak;
  Vout[(size_t)l * 128 + c] = av;
}

// out[row,:] = in[row,:Kdim] @ W[Kdim,128]
__global__ void k_rowgemm(const float* __restrict__ in, const float* __restrict__ W,
                          float* __restrict__ out, int Kdim) {
  __shared__ float rr[256];
  int row = blockIdx.x, c = threadIdx.x;
  for (int k = threadIdx.x; k < Kdim; k += 128) rr[k] = in[(size_t)row * Kdim + k];
  __syncthreads();
  float acc = 0.f;
  for (int k = 0; k < Kdim; ++k) acc += rr[k] * W[k * 128 + c];
  out[(size_t)row * 128 + c] = acc;
}

// ---------------------------------------------------------------- cross-attention, 4 graphs per block
__global__ void k_attn(const float* __restrict__ Q, const float* __restrict__ Kt,
                       const float* __restrict__ Vm, float* __restrict__ ctx) {
  __shared__ float q[4][128];
  __shared__ float sc[4][L];
  __shared__ float4 red[128];
  __shared__ float4 Mg, Ig;
  int b0 = blockIdx.x * 4, t = threadIdx.x;
#pragma unroll
  for (int g = 0; g < 4; ++g) q[g][t] = Q[(size_t)(b0 + g) * 128 + t];
  __syncthreads();
  float acc[4][4];
#pragma unroll
  for (int g = 0; g < 4; ++g)
#pragma unroll
    for (int j = 0; j < 4; ++j) acc[g][j] = 0.f;
  for (int k = 0; k < 128; ++k) {
    const float* kr = Kt + (size_t)k * L + t;
    float k0 = kr[0], k1 = kr[128], k2 = kr[256], k3 = kr[384];
#pragma unroll
    for (int g = 0; g < 4; ++g) {
      float qv = q[g][k];
      acc[g][0] += qv * k0; acc[g][1] += qv * k1;
      acc[g][2] += qv * k2; acc[g][3] += qv * k3;
    }
  }
  const float scale = 0.08838834764831845f;  // 1/sqrt(128)
  float4 pm;
  {
    float m[4];
#pragma unroll
    for (int g = 0; g < 4; ++g) {
#pragma unroll
      for (int j = 0; j < 4; ++j) {
        acc[g][j] *= scale;
        sc[g][t + j * 128] = acc[g][j];
      }
      m[g] = fmaxf(fmaxf(acc[g][0], acc[g][1]), fmaxf(acc[g][2], acc[g][3]));
    }
    pm = {m[0], m[1], m[2], m[3]};
  }
  red[t] = pm; __syncthreads();
  for (int s = 64; s > 0; s >>= 1) {
    if (t < s) {
      float4 o = red[t + s];
      red[t].x = fmaxf(red[t].x, o.x); red[t].y = fmaxf(red[t].y, o.y);
      red[t].z = fmaxf(red[t].z, o.z); red[t].w = fmaxf(red[t].w, o.w);
    }
    __syncthreads();
  }
  if (t == 0) Mg = red[0];
  __syncthreads();
  float4 M = Mg;
  float4 ps = {0, 0, 0, 0};
#pragma unroll
  for (int g = 0; g < 4; ++g) {
    float mg = (g == 0) ? M.x : (g == 1) ? M.y : (g == 2) ? M.z : M.w;
    float sgsum = 0.f;
#pragma unroll
    for (int j = 0; j < 4; ++j) {
      float e = __expf(acc[g][j] - mg);
      sc[g][t + j * 128] = e;
      sgsum += e;
    }
    if (g == 0) ps.x = sgsum; else if (g == 1) ps.y = sgsum;
    else if (g == 2) ps.z = sgsum; else ps.w = sgsum;
  }
  __syncthreads();  // sc writes done before PV reads
  red[t] = ps; __syncthreads();
  for (int s = 64; s > 0; s >>= 1) {
    if (t < s) {
      float4 o = red[t + s];
      red[t].x += o.x; red[t].y += o.y; red[t].z += o.z; red[t].w += o.w;
    }
    __syncthreads();
  }
  if (t == 0) Ig = {1.f / red[0].x, 1.f / red[0].y, 1.f / red[0].z, 1.f / red[0].w};
  __syncthreads();
  float4 I = Ig;
  float o0 = 0.f, o1 = 0.f, o2 = 0.f, o3 = 0.f;
  for (int l = 0; l < L; ++l) {
    float v = Vm[(size_t)l * 128 + t];
    o0 += sc[0][l] * v; o1 += sc[1][l] * v; o2 += sc[2][l] * v; o3 += sc[3][l] * v;
  }
  ctx[(size_t)(b0 + 0) * 128 + t] = o0 * I.x;
  ctx[(size_t)(b0 + 1) * 128 + t] = o1 * I.y;
  ctx[(size_t)(b0 + 2) * 128 + t] = o2 * I.z;
  ctx[(size_t)(b0 + 3) * 128 + t] = o3 * I.w;
}

// hh = concat(pooled, ctx) @ Wh1 + bh1
__global__ void k_head1(const float* __restrict__ pooled, const float* __restrict__ ctx,
                        const float* __restrict__ Wh1, const float* __restrict__ bh1,
                        float* __restrict__ hh) {
  __shared__ float f[256];
  int b = blockIdx.x, c = threadIdx.x;
  f[c] = pooled[(size_t)b * 128 + c];
  f[c + 128] = ctx[(size_t)b * 128 + c];
  __syncthreads();
  float acc = bh1[c];
  for (int k = 0; k < 256; ++k) acc += f[k] * Wh1[k * 128 + c];
  hh[(size_t)b * 128 + c] = acc;
}

// bn + leaky + final dot with Wh2 -> out[b*2+t]
__global__ void k_head2(const float* __restrict__ hh, const float* __restrict__ sums,
                        const float* __restrict__ sumsq, const float* __restrict__ g,
                        const float* __restrict__ bbn, const float* __restrict__ Wh2,
                        const float* __restrict__ bh2, float* __restrict__ out, int t,
                        float invn) {
  __shared__ float red[2];
  int b = blockIdx.x, c = threadIdx.x;
  float mu = sums[c] * invn;
  float var = sumsq[c] * invn - mu * mu;
  float y = (hh[(size_t)b * 128 + c] - mu) * rsqrtf(var + 1e-5f) * g[c] + bbn[c];
  y = (y > 0.f) ? y : 0.01f * y;
  float p = y * Wh2[c];
  for (int o = 32; o; o >>= 1) p += __shfl_down(p, o);
  if ((threadIdx.x & 63) == 0) red[threadIdx.x >> 6] = p;
  __syncthreads();
  if (threadIdx.x == 0) out[(size_t)b * 2 + t] = red[0] + red[1] + bh2[0];
}

extern "C" void kernel_launch(void* const* d_in, const int* in_sizes, int n_in,
                              void* d_out, int out_size, void* d_ws, size_t ws_size,
                              hipStream_t stream) {
  (void)n_in; (void)ws_size;
  const float* x     = (const float*)d_in[0];
  const int*   eidx  = (const int*)d_in[1];
  const float* eattr = (const float*)d_in[2];
  const int*   batch = (const int*)d_in[3];
  const float* eW1   = (const float*)d_in[4];
  const float* ea_s1 = (const float*)d_in[5];
  const float* ea_d1 = (const float*)d_in[6];
  const float* eWe1  = (const float*)d_in[7];
  const float* ea_e1 = (const float*)d_in[8];
  const float* eb1   = (const float*)d_in[9];
  const float* bn1_g = (const float*)d_in[10];
  const float* bn1_b = (const float*)d_in[11];
  const float* eW2   = (const float*)d_in[12];
  const float* ea_s2 = (const float*)d_in[13];
  const float* ea_d2 = (const float*)d_in[14];
  const float* eWe2  = (const float*)d_in[15];
  const float* ea_e2 = (const float*)d_in[16];
  const float* eb2   = (const float*)d_in[17];
  const float* bn2_g = (const float*)d_in[18];
  const float* bn2_b = (const float*)d_in[19];
  const float* gW    = (const float*)d_in[20];
  const float* ga_s  = (const float*)d_in[21];
  const float* ga_d  = (const float*)d_in[22];
  const float* gWe   = (const float*)d_in[23];
  const float* ga_e  = (const float*)d_in[24];
  const float* gb    = (const float*)d_in[25];
  const float* Wq    = (const float*)d_in[26];
  const float* Wk    = (const float*)d_in[27];
  const float* Wv    = (const float*)d_in[28];
  const float* pe    = (const float*)d_in[29];
  const float* Wh1   = (const float*)d_in[30];
  const float* bh1   = (const float*)d_in[31];
  const float* hbn_g = (const float*)d_in[32];
  const float* hbn_b = (const float*)d_in[33];
  const float* Wh2   = (const float*)d_in[34];
  const float* bh2   = (const float*)d_in[35];
  float* out = (float*)d_out;

  const int n = in_sizes[0] / DIN;    // 200000
  const int e = in_sizes[1] / 2;      // 800000
  const int nb_graphs = out_size / 2; // 4096
  const int* src = eidx;
  const int* dst = eidx + e;

  char* p = (char*)d_ws;
  auto carve = [&](size_t bytes) {
    void* r = (void*)p;
    p += (bytes + 255) & ~(size_t)255;
    return r;
  };
  int* deg       = (int*)carve((size_t)n * 4);
  int* off       = (int*)carve(((size_t)n + 1) * 4);
  int* cursor    = (int*)carve((size_t)n * 4);
  int* eid       = (int*)carve((size_t)e * 4);
  int* bsum      = (int*)carve(4096);
  int* src_csr   = (int*)carve((size_t)e * 4);
  int* dst_csr   = (int*)carve((size_t)e * 4);
  float* edots   = (float*)carve((size_t)14 * e * 4);
  float* weall   = (float*)carve(14 * 16 * 4);
  float* s_arr   = (float*)carve((size_t)n * 4);
  float* d_arr   = (float*)carve((size_t)n * 4);
  float* lcsr    = (float*)carve((size_t)e * 4);
  float* sums    = (float*)carve(256 * 4);
  float* gates0  = (float*)carve((size_t)n * 16);
  float* gates1  = (float*)carve((size_t)n * 16);
  float* gfeat   = (float*)carve((size_t)n * 16);
  float* pooled0 = (float*)carve((size_t)nb_graphs * H * 4);
  float* pooled1 = (float*)carve((size_t)nb_graphs * H * 4);
  float* Ktbuf   = (float*)carve((size_t)L * H * 4);
  float* Vbuf    = (float*)carve((size_t)L * H * 4);
  float* Qbuf    = (float*)carve((size_t)nb_graphs * H * 4);
  float* ctxb    = (float*)carve((size_t)nb_graphs * H * 4);
  float* hhb     = (float*)carve((size_t)nb_graphs * H * 4);
  bf16* featbuf  = (bf16*)carve((size_t)n * H * 2);
  bf16* buf1     = (bf16*)carve((size_t)n * H * 2);

  float invn = 1.0f / n;

  // ---- CSR by dst (reused by all 14 GAT convs)
  k_zero_i32<<<(n + 255) / 256, 256, 0, stream>>>(deg, n);
  k_deg<<<(e + 255) / 256, 256, 0, stream>>>(dst, deg, e);
  int nsb = (n + 511) / 512;
  k_scan1<<<nsb, 512, 0, stream>>>(deg, off, bsum, n);
  k_scan2<<<1, 512, 0, stream>>>(bsum, nsb);
  k_scan3<<<nsb, 512, 0, stream>>>(off, bsum, cursor, n, e);
  k_fill<<<(e + 255) / 256, 256, 0, stream>>>(dst, cursor, eid, e);

  // ---- all 14 edge-weight dots in CSR order (single eattr pass)
  k_weall<<<1, 256, 0, stream>>>(gWe, ga_e, eWe1, ea_e1, eWe2, ea_e2, weall);
  k_csrprep<<<(e + 255) / 256, 256, 0, stream>>>(eid, src, dst, eattr, weall, src_csr,
                                                 dst_csr, edots, e);

  // ---- gates (2 tasks; edots cols 0,1)
  for (int t = 0; t < 2; ++t) {
    float* gates = t ? gates1 : gates0;
    k_gfeat<<<(n + 255) / 256, 256, 0, stream>>>(x, gW + t * DIN * 4, ga_s + t * 4,
                                                 ga_d + t * 4, gfeat, s_arr, d_arr, n);
    k_edge_l<<<(e + 255) / 256, 256, 0, stream>>>(src_csr, dst_csr, edots + (size_t)t * e,
                                                  s_arr, d_arr, lcsr, e);
    k_agg4<<<(n + 255) / 256, 256, 0, stream>>>(off, src_csr, lcsr, gfeat, gb + t * 4,
                                                gates, n);
  }

  // ---- zero pooled accumulators
  k_zero_f32<<<(nb_graphs * H + 255) / 256, 256, 0, stream>>>(pooled0, nb_graphs * H);
  k_zero_f32<<<(nb_graphs * H + 255) / 256, 256, 0, stream>>>(pooled1, nb_graphs * H);

  // ---- 6 experts (bf16 node buffers), fused BN2+gate+pool epilogue
  int nquads = n * 32;  // n*128/4
  for (int i = 0; i < 6; ++i) {
    // layer 1 (DIN -> H), x is fp32
    k_gemm128<DIN, float><<<(n + 15) / 16, 256, 0, stream>>>(x, eW1 + i * DIN * H,
                                                             featbuf, n);
    k_sd<<<(n + 3) / 4, 256, 0, stream>>>(featbuf, ea_s1 + i * H, ea_d1 + i * H, s_arr,
                                          d_arr, n);
    k_edge_l<<<(e + 255) / 256, 256, 0, stream>>>(src_csr, dst_csr,
                                                  edots + (size_t)(2 + i) * e, s_arr,
                                                  d_arr, lcsr, e);
    k_agg128<<<(n + 7) / 8, 256, 0, stream>>>(off, src_csr, lcsr, featbuf, eb1 + i * H,
                                              buf1, n);
    k_zero_f32<<<1, 256, 0, stream>>>(sums, 256);
    k_bnstats_bf<<<1024, 256, 0, stream>>>(buf1, sums, sums + 128, n);
    k_bnapply_bf<<<(nquads + 255) / 256, 256, 0, stream>>>(buf1, sums, sums + 128,
                                                           bn1_g + i * H, bn1_b + i * H,
                                                           nquads, invn);
    // layer 2 (H -> H), bf16 in
    k_gemm128<H, bf16><<<(n + 15) / 16, 256, 0, stream>>>(buf1, eW2 + i * H * H,
                                                          featbuf, n);
    k_sd<<<(n + 3) / 4, 256, 0, stream>>>(featbuf, ea_s2 + i * H, ea_d2 + i * H, s_arr,
                                          d_arr, n);
    k_edge_l<<<(e + 255) / 256, 256, 0, stream>>>(src_csr, dst_csr,
                                                  edots + (size_t)(8 + i) * e, s_arr,
                                                  d_arr, lcsr, e);
    k_agg128<<<(n + 7) / 8, 256, 0, stream>>>(off, src_csr, lcsr, featbuf, eb2 + i * H,
                                              buf1, n);
    k_zero_f32<<<1, 256, 0, stream>>>(sums, 256);
    k_bnstats_bf<<<1024, 256, 0, stream>>>(buf1, sums, sums + 128, n);
    int s0 = (i < 4) ? i : -1;                     // task0: experts 0,1,2,3
    int s1 = (i < 2) ? i : (i >= 4 ? i - 2 : -1);  // task1: experts 0,1,4,5
    k_poolexpert<<<nb_graphs, 64, 0, stream>>>(buf1, sums, sums + 128, bn2_g + i * H,
                                               bn2_b + i * H, batch, gates0, s0, gates1,
                                               s1, pooled0, pooled1, n, invn);
  }

  // ---- heads
  for (int t = 0; t < 2; ++t) {
    const float* pooled = t ? pooled1 : pooled0;
    k_kv<<<L, 128, 0, stream>>>(pe + (size_t)t * L * PD, Wk + t * PD * H, Wv + t * PD * H,
                                Ktbuf, Vbuf);
    k_rowgemm<<<nb_graphs, 128, 0, stream>>>(pooled, Wq + t * H * H, Qbuf, H);
    k_attn<<<nb_graphs / 4, 128, 0, stream>>>(Qbuf, Ktbuf, Vbuf, ctxb);
    k_head1<<<nb_graphs, 128, 0, stream>>>(pooled, ctxb, Wh1 + t * 2 * H * H, bh1 + t * H,
                                           hhb);
    k_zero_f32<<<1, 256, 0, stream>>>(sums, 256);
    k_bnstats_f32<<<256, 256, 0, stream>>>(hhb, sums, sums + 128, nb_graphs);
    k_head2<<<nb_graphs, 128, 0, stream>>>(hhb, sums, sums + 128, hbn_g + t * H,
                                           hbn_b + t * H, Wh2 + t * H, bh2 + t, out, t,
                                           1.0f / nb_graphs);
  }
}

// Round 4
// 3842.247 us; speedup vs baseline: 1.6463x; 1.3009x over previous
//
#include <hip/hip_runtime.h>
#include <hip/hip_bf16.h>
#include <cstdint>
#include <cstddef>
#include <type_traits>

constexpr int DIN = 64;
constexpr int DE  = 16;
constexpr int H   = 128;
constexpr int L   = 512;
constexpr int PD  = 1152;

using bf16 = __hip_bfloat16;
typedef __attribute__((ext_vector_type(8))) short short8;
typedef __attribute__((ext_vector_type(4))) float float4v;

// ---- bf16 pack/unpack helpers (bf16x2 in a uint) ----
__device__ __forceinline__ float bflo(unsigned u) { return __uint_as_float(u << 16); }
__device__ __forceinline__ float bfhi(unsigned u) { return __uint_as_float(u & 0xffff0000u); }
__device__ __forceinline__ unsigned short f2b(float f) {
  bf16 h = __float2bfloat16(f);
  return *reinterpret_cast<unsigned short*>(&h);
}
__device__ __forceinline__ unsigned pack2(float a, float b) {
  return (unsigned)f2b(a) | ((unsigned)f2b(b) << 16);
}

// ---------------------------------------------------------------- zero fill
__global__ void k_zero_i32(int* p, int n) {
  int i = blockIdx.x * 256 + threadIdx.x;
  if (i < n) p[i] = 0;
}
__global__ void k_zero_f32(float* p, int n) {
  int i = blockIdx.x * 256 + threadIdx.x;
  if (i < n) p[i] = 0.f;
}

// fp32 -> bf16 (2 elements per thread)
__global__ void k_cvt_bf16(const float* __restrict__ in, bf16* __restrict__ out, int npairs) {
  int i = blockIdx.x * 256 + threadIdx.x;
  if (i >= npairs) return;
  float2 v = ((const float2*)in)[i];
  ((unsigned*)out)[i] = pack2(v.x, v.y);
}

// ---------------------------------------------------------------- CSR build
__global__ void k_deg(const int* __restrict__ dst, int* __restrict__ deg, int e) {
  int i = blockIdx.x * 256 + threadIdx.x;
  if (i < e) atomicAdd(&deg[dst[i]], 1);
}

__global__ void k_scan1(const int* __restrict__ deg, int* __restrict__ out,
                        int* __restrict__ bsum, int n) {
  __shared__ int tmp[512];
  int tid = threadIdx.x;
  int i = blockIdx.x * 512 + tid;
  int v = (i < n) ? deg[i] : 0;
  tmp[tid] = v; __syncthreads();
  for (int s = 1; s < 512; s <<= 1) {
    int t = (tid >= s) ? tmp[tid - s] : 0;
    __syncthreads();
    tmp[tid] += t;
    __syncthreads();
  }
  if (i < n) out[i] = tmp[tid] - v;
  if (tid == 511) bsum[blockIdx.x] = tmp[511];
}

__global__ void k_scan2(int* bsum, int nb) {  // nb <= 512
  __shared__ int tmp[512];
  int tid = threadIdx.x;
  int v = (tid < nb) ? bsum[tid] : 0;
  tmp[tid] = v; __syncthreads();
  for (int s = 1; s < 512; s <<= 1) {
    int t = (tid >= s) ? tmp[tid - s] : 0;
    __syncthreads();
    tmp[tid] += t;
    __syncthreads();
  }
  if (tid < nb) bsum[tid] = tmp[tid] - v;
}

__global__ void k_scan3(int* __restrict__ off, const int* __restrict__ bsum,
                        int* __restrict__ cursor, int n, int total) {
  int i = blockIdx.x * 512 + threadIdx.x;
  if (i < n) { int v = off[i] + bsum[blockIdx.x]; off[i] = v; cursor[i] = v; }
  if (i == 0) off[n] = total;
}

__global__ void k_fill(const int* __restrict__ dst, int* __restrict__ cursor,
                       int* __restrict__ eid, int e) {
  int i = blockIdx.x * 256 + threadIdx.x;
  if (i < e) { int slot = atomicAdd(&cursor[dst[i]], 1); eid[slot] = i; }
}

// ---------------------------------------------------------------- weall: all 14 conv edge-weight vectors [14][16]
__global__ void k_weall(const float* __restrict__ gWe, const float* __restrict__ ga_e,
                        const float* __restrict__ eWe1, const float* __restrict__ ea_e1,
                        const float* __restrict__ eWe2, const float* __restrict__ ea_e2,
                        float* __restrict__ weall) {
  int tid = threadIdx.x;
  if (tid >= 14 * 16) return;
  int c = tid >> 4, j = tid & 15;
  float acc = 0.f;
  if (c < 2) {
    for (int k = 0; k < 4; ++k) acc += gWe[(c * 16 + j) * 4 + k] * ga_e[c * 4 + k];
  } else if (c < 8) {
    int i = c - 2;
    for (int k = 0; k < 128; ++k) acc += eWe1[(i * 16 + j) * 128 + k] * ea_e1[i * 128 + k];
  } else {
    int i = c - 8;
    for (int k = 0; k < 128; ++k) acc += eWe2[(i * 16 + j) * 128 + k] * ea_e2[i * 128 + k];
  }
  weall[c * 16 + j] = acc;
}

// ---------------------------------------------------------------- weight repack into MFMA B-frag order (bf16)
// frag element (kt,nt,l,j)  <-  W[kt*32 + (l>>4)*8 + j][nt*16 + (l&15)]
// layer1: per-expert 2*8*64*8 = 8192 elems; layer2: 4*8*64*8 = 16384
__global__ void k_wpackall(const float* __restrict__ eW1, const float* __restrict__ eW2,
                           bf16* __restrict__ Wp1, bf16* __restrict__ Wp2) {
  int tid = blockIdx.x * 256 + threadIdx.x;
  const int L1TOT = 6 * 8192;
  if (tid < L1TOT) {
    int i = tid / 8192, r = tid % 8192;
    int kt = r / 4096, nt = (r / 512) & 7, l = (r / 8) & 63, j = r & 7;
    int k = kt * 32 + (l >> 4) * 8 + j, col = nt * 16 + (l & 15);
    Wp1[tid] = __float2bfloat16(eW1[(size_t)i * 64 * 128 + k * 128 + col]);
  } else {
    int t2 = tid - L1TOT;
    if (t2 >= 6 * 16384) return;
    int i = t2 / 16384, r = t2 % 16384;
    int kt = r / 4096, nt = (r / 512) & 7, l = (r / 8) & 63, j = r & 7;
    int k = kt * 32 + (l >> 4) * 8 + j, col = nt * 16 + (l & 15);
    Wp2[t2] = __float2bfloat16(eW2[(size_t)i * 128 * 128 + k * 128 + col]);
  }
}

// ---------------------------------------------------------------- CSR prep: src/dst in CSR order + all 14 edots
__global__ void k_csrprep(const int* __restrict__ eid, const int* __restrict__ src,
                          const int* __restrict__ dst, const float* __restrict__ eattr,
                          const float* __restrict__ weall, int* __restrict__ src_csr,
                          int* __restrict__ dst_csr, float* __restrict__ edots, int e) {
  __shared__ float w[14 * 16];
  if (threadIdx.x < 14 * 16) w[threadIdx.x] = weall[threadIdx.x];
  __syncthreads();
  int i = blockIdx.x * 256 + threadIdx.x;
  if (i >= e) return;
  int ed = eid[i];
  src_csr[i] = src[ed];
  dst_csr[i] = dst[ed];
  float ea[16];
  const float4* ep = (const float4*)(eattr + (size_t)ed * 16);
#pragma unroll
  for (int q = 0; q < 4; ++q) {
    float4 v = ep[q];
    ea[q * 4] = v.x; ea[q * 4 + 1] = v.y; ea[q * 4 + 2] = v.z; ea[q * 4 + 3] = v.w;
  }
#pragma unroll
  for (int c = 0; c < 14; ++c) {
    float acc = 0.f;
#pragma unroll
    for (int j = 0; j < 16; ++j) acc += ea[j] * w[c * 16 + j];
    edots[(size_t)c * e + i] = acc;
  }
}

// ---------------------------------------------------------------- MFMA GEMM: out[N,128](bf16) = A[N,K](bf16) @ W(packed)
// also fuses s[n] = out_row . a_s, d[n] = out_row . a_d  (pre-bf16-rounding)
template <int K>
__global__ __launch_bounds__(256) void k_mfma_gemm(
    const bf16* __restrict__ A, const bf16* __restrict__ Wp,
    const float* __restrict__ a_s, const float* __restrict__ a_d,
    bf16* __restrict__ out, float* __restrict__ s, float* __restrict__ d, int n) {
  constexpr int KT = K / 32;
  __shared__ bf16 At[64][K + 8];  // row stride (K+8)*2 bytes, multiple of 16
  int row0 = blockIdx.x * 64;
  const int vecPerRow = K / 8;  // uint4 (8 bf16) per row
  for (int idx = threadIdx.x; idx < 64 * vecPerRow; idx += 256) {
    int r = idx / vecPerRow, v = idx - r * vecPerRow;
    int gr = row0 + r;
    uint4 u = {0u, 0u, 0u, 0u};
    if (gr < n) u = ((const uint4*)(A + (size_t)gr * K))[v];
    *((uint4*)&At[r][v * 8]) = u;
  }
  __syncthreads();
  int lane = threadIdx.x & 63, w = threadIdx.x >> 6;
  int c = lane & 15, q = lane >> 4;
  int wrow = w * 16;
  short8 afrag[KT];
#pragma unroll
  for (int kt = 0; kt < KT; ++kt)
    afrag[kt] = *(const short8*)&At[wrow + c][kt * 32 + q * 8];
  const short8* wp8 = (const short8*)Wp;
  float4v acc[8];
#pragma unroll
  for (int nt = 0; nt < 8; ++nt) acc[nt] = {0.f, 0.f, 0.f, 0.f};
#pragma unroll
  for (int kt = 0; kt < KT; ++kt) {
#pragma unroll
    for (int nt = 0; nt < 8; ++nt) {
      short8 bfrag = wp8[(kt * 8 + nt) * 64 + lane];
      acc[nt] = __builtin_amdgcn_mfma_f32_16x16x32_bf16(afrag[kt], bfrag, acc[nt], 0, 0, 0);
    }
  }
  // store C: lane holds col c, rows q*4+reg
#pragma unroll
  for (int nt = 0; nt < 8; ++nt) {
#pragma unroll
    for (int reg = 0; reg < 4; ++reg) {
      int gr = row0 + wrow + q * 4 + reg;
      if (gr < n) out[(size_t)gr * 128 + nt * 16 + c] = __float2bfloat16(acc[nt][reg]);
    }
  }
  // fused s/d: row fully within wave; reduce over the 16 lanes holding this row
#pragma unroll
  for (int reg = 0; reg < 4; ++reg) {
    float vs = 0.f, vd = 0.f;
#pragma unroll
    for (int nt = 0; nt < 8; ++nt) {
      float y = acc[nt][reg];
      int col = nt * 16 + c;
      vs += y * a_s[col];
      vd += y * a_d[col];
    }
#pragma unroll
    for (int o = 1; o < 16; o <<= 1) { vs += __shfl_xor(vs, o); vd += __shfl_xor(vd, o); }
    int gr = row0 + wrow + q * 4 + reg;
    if (c == 0 && gr < n) { s[gr] = vs; d[gr] = vd; }
  }
}

// ---------------------------------------------------------------- edge logits in CSR order
__global__ void k_edge_l(const int* __restrict__ src_csr, const int* __restrict__ dst_csr,
                         const float* __restrict__ edot, const float* __restrict__ s,
                         const float* __restrict__ d, float* __restrict__ lcsr, int e) {
  int i = blockIdx.x * 256 + threadIdx.x;
  if (i >= e) return;
  float l = s[src_csr[i]] + d[dst_csr[i]] + edot[i];
  lcsr[i] = (l > 0.f) ? l : 0.2f * l;
}

// ---------------------------------------------------------------- agg: softmax over incoming + gather (32 lanes/node)
__global__ void k_agg128(const int* __restrict__ off, const int* __restrict__ src_csr,
                         const float* __restrict__ lcsr, const bf16* __restrict__ feat,
                         const float* __restrict__ bias, bf16* __restrict__ out, int n) {
  int node = blockIdx.x * 8 + (threadIdx.x >> 5);
  int lane = threadIdx.x & 31;
  if (node >= n) return;
  int e0 = off[node], e1 = off[node + 1];
  float m = -INFINITY;
  for (int i = e0 + lane; i < e1; i += 32) m = fmaxf(m, lcsr[i]);
  for (int o = 16; o; o >>= 1) m = fmaxf(m, __shfl_xor(m, o));
  float den = 0.f;
  for (int i = e0 + lane; i < e1; i += 32) den += __expf(lcsr[i] - m);
  for (int o = 16; o; o >>= 1) den += __shfl_xor(den, o);
  float inv = 1.0f / (den + 1e-16f);
  float4 acc = {0.f, 0.f, 0.f, 0.f};
  for (int i = e0; i < e1; ++i) {
    float alpha = __expf(lcsr[i] - m) * inv;
    const uint2* fr = (const uint2*)(feat + (size_t)src_csr[i] * 128);
    uint2 u = fr[lane];
    acc.x += alpha * bflo(u.x);
    acc.y += alpha * bfhi(u.x);
    acc.z += alpha * bflo(u.y);
    acc.w += alpha * bfhi(u.y);
  }
  float4 b4 = ((const float4*)bias)[lane];
  uint2 o2;
  o2.x = pack2(acc.x + b4.x, acc.y + b4.y);
  o2.y = pack2(acc.z + b4.z, acc.w + b4.w);
  ((uint2*)(out + (size_t)node * 128))[lane] = o2;
}

// ---------------------------------------------------------------- gate feature + s/d
__global__ void k_gfeat(const float* __restrict__ x, const float* __restrict__ W,
                        const float* __restrict__ a_s, const float* __restrict__ a_d,
                        float* __restrict__ gfeat, float* __restrict__ s,
                        float* __restrict__ d, int n) {
  int i = blockIdx.x * 256 + threadIdx.x;
  if (i >= n) return;
  const float* xr = x + (size_t)i * DIN;
  float acc[4] = {0.f, 0.f, 0.f, 0.f};
  for (int k = 0; k < DIN; ++k) {
    float xv = xr[k];
#pragma unroll
    for (int j = 0; j < 4; ++j) acc[j] += xv * W[k * 4 + j];
  }
  float ss = 0.f, dd = 0.f;
#pragma unroll
  for (int j = 0; j < 4; ++j) {
    gfeat[(size_t)i * 4 + j] = acc[j];
    ss += acc[j] * a_s[j];
    dd += acc[j] * a_d[j];
  }
  s[i] = ss; d[i] = dd;
}

// ---------------------------------------------------------------- gate aggregation + channel softmax
__global__ void k_agg4(const int* __restrict__ off, const int* __restrict__ src_csr,
                       const float* __restrict__ lcsr, const float* __restrict__ gfeat,
                       const float* __restrict__ bias, float* __restrict__ gates, int n) {
  int node = blockIdx.x * 256 + threadIdx.x;
  if (node >= n) return;
  int e0 = off[node], e1 = off[node + 1];
  float m = -INFINITY;
  for (int i = e0; i < e1; ++i) m = fmaxf(m, lcsr[i]);
  float den = 0.f;
  for (int i = e0; i < e1; ++i) den += __expf(lcsr[i] - m);
  float inv = 1.f / (den + 1e-16f);
  float4 acc = {0.f, 0.f, 0.f, 0.f};
  for (int i = e0; i < e1; ++i) {
    float a = __expf(lcsr[i] - m) * inv;
    float4 fr = *((const float4*)(gfeat + (size_t)src_csr[i] * 4));
    acc.x += a * fr.x; acc.y += a * fr.y; acc.z += a * fr.z; acc.w += a * fr.w;
  }
  float b0 = bias[0], b1 = bias[1], b2 = bias[2], b3 = bias[3];
  acc.x += b0; acc.y += b1; acc.z += b2; acc.w += b3;
  float mm = fmaxf(fmaxf(acc.x, acc.y), fmaxf(acc.z, acc.w));
  float e0s = __expf(acc.x - mm), e1s = __expf(acc.y - mm);
  float e2s = __expf(acc.z - mm), e3s = __expf(acc.w - mm);
  float is = 1.f / (e0s + e1s + e2s + e3s);
  float4 g4 = {e0s * is, e1s * is, e2s * is, e3s * is};
  *((float4*)(gates + (size_t)node * 4)) = g4;
}

// ---------------------------------------------------------------- BN stats (bf16, vectorized)
__global__ void k_bnstats_bf(const bf16* __restrict__ x, float* __restrict__ sums,
                             float* __restrict__ sumsq, int n) {
  __shared__ float4 sA[256], sB[256];
  int qc = threadIdx.x & 31;
  int rg = threadIdx.x >> 5;
  float4 a = {0, 0, 0, 0}, b = {0, 0, 0, 0};
  for (int r = blockIdx.x * 8 + rg; r < n; r += gridDim.x * 8) {
    uint2 u = ((const uint2*)(x + (size_t)r * 128))[qc];
    float f0 = bflo(u.x), f1 = bfhi(u.x), f2 = bflo(u.y), f3 = bfhi(u.y);
    a.x += f0; a.y += f1; a.z += f2; a.w += f3;
    b.x += f0 * f0; b.y += f1 * f1; b.z += f2 * f2; b.w += f3 * f3;
  }
  sA[threadIdx.x] = a; sB[threadIdx.x] = b;
  __syncthreads();
  if (rg == 0) {
#pragma unroll
    for (int g = 1; g < 8; ++g) {
      float4 ta = sA[g * 32 + qc], tb = sB[g * 32 + qc];
      a.x += ta.x; a.y += ta.y; a.z += ta.z; a.w += ta.w;
      b.x += tb.x; b.y += tb.y; b.z += tb.z; b.w += tb.w;
    }
    int c = qc * 4;
    atomicAdd(&sums[c], a.x); atomicAdd(&sums[c + 1], a.y);
    atomicAdd(&sums[c + 2], a.z); atomicAdd(&sums[c + 3], a.w);
    atomicAdd(&sumsq[c], b.x); atomicAdd(&sumsq[c + 1], b.y);
    atomicAdd(&sumsq[c + 2], b.z); atomicAdd(&sumsq[c + 3], b.w);
  }
}

// BN stats fp32 (head path)
__global__ void k_bnstats_f32(const float* __restrict__ x, float* __restrict__ sums,
                              float* __restrict__ sumsq, int n) {
  __shared__ float s1[256], s2[256];
  int c = threadIdx.x & 127, half = threadIdx.x >> 7;
  float a = 0.f, b = 0.f;
  for (int r = blockIdx.x * 2 + half; r < n; r += gridDim.x * 2) {
    float v = x[(size_t)r * 128 + c];
    a += v; b += v * v;
  }
  s1[threadIdx.x] = a; s2[threadIdx.x] = b;
  __syncthreads();
  if (half == 0) {
    atomicAdd(&sums[c], s1[c] + s1[c + 128]);
    atomicAdd(&sumsq[c], s2[c] + s2[c + 128]);
  }
}

// ---------------------------------------------------------------- BN apply + leaky (bf16 in place)
__global__ void k_bnapply_bf(bf16* __restrict__ x, const float* __restrict__ sums,
                             const float* __restrict__ sumsq, const float* __restrict__ g,
                             const float* __restrict__ b, int nquads, float invn) {
  int idx = blockIdx.x * 256 + threadIdx.x;
  if (idx >= nquads) return;
  int c = (idx & 31) * 4;
  uint2 u = ((uint2*)x)[idx];
  float y[4] = {bflo(u.x), bfhi(u.x), bflo(u.y), bfhi(u.y)};
#pragma unroll
  for (int k = 0; k < 4; ++k) {
    float mu = sums[c + k] * invn;
    float var = sumsq[c + k] * invn - mu * mu;
    float v = (y[k] - mu) * rsqrtf(var + 1e-5f) * g[c + k] + b[c + k];
    y[k] = (v > 0.f) ? v : 0.01f * v;
  }
  uint2 o;
  o.x = pack2(y[0], y[1]);
  o.y = pack2(y[2], y[3]);
  ((uint2*)x)[idx] = o;
}

// ---------------------------------------------------------------- fused BN2+leaky+gate+pool
__global__ void k_poolexpert(const bf16* __restrict__ x, const float* __restrict__ sums,
                             const float* __restrict__ sumsq, const float* __restrict__ g,
                             const float* __restrict__ bb, const int* __restrict__ batch,
                             const float* __restrict__ gates0, int slot0,
                             const float* __restrict__ gates1, int slot1,
                             float* __restrict__ pooled0, float* __restrict__ pooled1,
                             int n, float invn) {
  int b = blockIdx.x, t = threadIdx.x;
  int lo = 0, hi = n;
  while (lo < hi) { int m = (lo + hi) >> 1; if (batch[m] < b) lo = m + 1; else hi = m; }
  int start = lo;
  lo = start; hi = n;
  while (lo < hi) { int m = (lo + hi) >> 1; if (batch[m] < b + 1) lo = m + 1; else hi = m; }
  int end = lo;
  int c0 = 2 * t, c1 = 2 * t + 1;
  float mu0 = sums[c0] * invn, mu1 = sums[c1] * invn;
  float sc0 = rsqrtf(sumsq[c0] * invn - mu0 * mu0 + 1e-5f) * g[c0];
  float sc1 = rsqrtf(sumsq[c1] * invn - mu1 * mu1 + 1e-5f) * g[c1];
  float sh0 = bb[c0], sh1 = bb[c1];
  float a00 = 0.f, a01 = 0.f, a10 = 0.f, a11 = 0.f;
  for (int r = start; r < end; ++r) {
    unsigned u = ((const unsigned*)(x + (size_t)r * 128))[t];
    float y0 = (bflo(u) - mu0) * sc0 + sh0;
    float y1 = (bfhi(u) - mu1) * sc1 + sh1;
    y0 = (y0 > 0.f) ? y0 : 0.01f * y0;
    y1 = (y1 > 0.f) ? y1 : 0.01f * y1;
    if (slot0 >= 0) {
      float gw = gates0[(size_t)r * 4 + slot0];
      a00 += gw * y0; a01 += gw * y1;
    }
    if (slot1 >= 0) {
      float gw = gates1[(size_t)r * 4 + slot1];
      a10 += gw * y0; a11 += gw * y1;
    }
  }
  if (slot0 >= 0) {
    pooled0[(size_t)b * 128 + c0] += a00;
    pooled0[(size_t)b * 128 + c1] += a01;
  }
  if (slot1 >= 0) {
    pooled1[(size_t)b * 128 + c0] += a10;
    pooled1[(size_t)b * 128 + c1] += a11;
  }
}

// ---------------------------------------------------------------- K^T = (pe@Wk)^T [128][L], V = pe@Wv [L][128]
__global__ void k_kv(const float* __restrict__ pe, const float* __restrict__ Wk,
                     const float* __restrict__ Wv, float* __restrict__ Kt,
                     float* __restrict__ Vout) {
  __shared__ float per[PD];
  int l = blockIdx.x, c = threadIdx.x;
  for (int p = threadIdx.x; p < PD; p += 128) per[p] = pe[(size_t)l * PD + p];
  __syncthreads();
  float ak = 0.f, av = 0.f;
  for (int p = 0; p < PD; ++p) {
    float v = per[p];
    ak += v * Wk[p * 128 + c];
    av += v * Wv[p * 128 + c];
  }
  Kt[(size_t)c * L + l] = ak;
  Vout[(size_t)l * 128 + c] = av;
}

// out[row,:] = in[row,:Kdim] @ W[Kdim,128]
__global__ void k_rowgemm(const float* __restrict__ in, const float* __restrict__ W,
                          float* __restrict__ out, int Kdim) {
  __shared__ float rr[256];
  int row = blockIdx.x, c = threadIdx.x;
  for (int k = threadIdx.x; k < Kdim; k += 128) rr[k] = in[(size_t)row * Kdim + k];
  __syncthreads();
  float acc = 0.f;
  for (int k = 0; k < Kdim; ++k) acc += rr[k] * W[k * 128 + c];
  out[(size_t)row * 128 + c] = acc;
}

// ---------------------------------------------------------------- cross-attention, 4 graphs per block
__global__ void k_attn(const float* __restrict__ Q, const float* __restrict__ Kt,
                       const float* __restrict__ Vm, float* __restrict__ ctx) {
  __shared__ float q[4][128];
  __shared__ float sc[4][L];
  __shared__ float4 red[128];
  __shared__ float4 Mg, Ig;
  int b0 = blockIdx.x * 4, t = threadIdx.x;
#pragma unroll
  for (int g = 0; g < 4; ++g) q[g][t] = Q[(size_t)(b0 + g) * 128 + t];
  __syncthreads();
  float acc[4][4];
#pragma unroll
  for (int g = 0; g < 4; ++g)
#pragma unroll
    for (int j = 0; j < 4; ++j) acc[g][j] = 0.f;
  for (int k = 0; k < 128; ++k) {
    const float* kr = Kt + (size_t)k * L + t;
    float k0 = kr[0], k1 = kr[128], k2 = kr[256], k3 = kr[384];
#pragma unroll
    for (int g = 0; g < 4; ++g) {
      float qv = q[g][k];
      acc[g][0] += qv * k0; acc[g][1] += qv * k1;
      acc[g][2] += qv * k2; acc[g][3] += qv * k3;
    }
  }
  const float scale = 0.08838834764831845f;
  float4 pm;
  {
    float m[4];
#pragma unroll
    for (int g = 0; g < 4; ++g) {
#pragma unroll
      for (int j = 0; j < 4; ++j) {
        acc[g][j] *= scale;
        sc[g][t + j * 128] = acc[g][j];
      }
      m[g] = fmaxf(fmaxf(acc[g][0], acc[g][1]), fmaxf(acc[g][2], acc[g][3]));
    }
    pm = {m[0], m[1], m[2], m[3]};
  }
  red[t] = pm; __syncthreads();
  for (int s = 64; s > 0; s >>= 1) {
    if (t < s) {
      float4 o = red[t + s];
      red[t].x = fmaxf(red[t].x, o.x); red[t].y = fmaxf(red[t].y, o.y);
      red[t].z = fmaxf(red[t].z, o.z); red[t].w = fmaxf(red[t].w, o.w);
    }
    __syncthreads();
  }
  if (t == 0) Mg = red[0];
  __syncthreads();
  float4 M = Mg;
  float4 ps = {0, 0, 0, 0};
#pragma unroll
  for (int g = 0; g < 4; ++g) {
    float mg = (g == 0) ? M.x : (g == 1) ? M.y : (g == 2) ? M.z : M.w;
    float sgsum = 0.f;
#pragma unroll
    for (int j = 0; j < 4; ++j) {
      float e = __expf(acc[g][j] - mg);
      sc[g][t + j * 128] = e;
      sgsum += e;
    }
    if (g == 0) ps.x = sgsum; else if (g == 1) ps.y = sgsum;
    else if (g == 2) ps.z = sgsum; else ps.w = sgsum;
  }
  __syncthreads();
  red[t] = ps; __syncthreads();
  for (int s = 64; s > 0; s >>= 1) {
    if (t < s) {
      float4 o = red[t + s];
      red[t].x += o.x; red[t].y += o.y; red[t].z += o.z; red[t].w += o.w;
    }
    __syncthreads();
  }
  if (t == 0) Ig = {1.f / red[0].x, 1.f / red[0].y, 1.f / red[0].z, 1.f / red[0].w};
  __syncthreads();
  float4 I = Ig;
  float o0 = 0.f, o1 = 0.f, o2 = 0.f, o3 = 0.f;
  for (int l = 0; l < L; ++l) {
    float v = Vm[(size_t)l * 128 + t];
    o0 += sc[0][l] * v; o1 += sc[1][l] * v; o2 += sc[2][l] * v; o3 += sc[3][l] * v;
  }
  ctx[(size_t)(b0 + 0) * 128 + t] = o0 * I.x;
  ctx[(size_t)(b0 + 1) * 128 + t] = o1 * I.y;
  ctx[(size_t)(b0 + 2) * 128 + t] = o2 * I.z;
  ctx[(size_t)(b0 + 3) * 128 + t] = o3 * I.w;
}

// hh = concat(pooled, ctx) @ Wh1 + bh1
__global__ void k_head1(const float* __restrict__ pooled, const float* __restrict__ ctx,
                        const float* __restrict__ Wh1, const float* __restrict__ bh1,
                        float* __restrict__ hh) {
  __shared__ float f[256];
  int b = blockIdx.x, c = threadIdx.x;
  f[c] = pooled[(size_t)b * 128 + c];
  f[c + 128] = ctx[(size_t)b * 128 + c];
  __syncthreads();
  float acc = bh1[c];
  for (int k = 0; k < 256; ++k) acc += f[k] * Wh1[k * 128 + c];
  hh[(size_t)b * 128 + c] = acc;
}

// bn + leaky + final dot with Wh2 -> out[b*2+t]
__global__ void k_head2(const float* __restrict__ hh, const float* __restrict__ sums,
                        const float* __restrict__ sumsq, const float* __restrict__ g,
                        const float* __restrict__ bbn, const float* __restrict__ Wh2,
                        const float* __restrict__ bh2, float* __restrict__ out, int t,
                        float invn) {
  __shared__ float red[2];
  int b = blockIdx.x, c = threadIdx.x;
  float mu = sums[c] * invn;
  float var = sumsq[c] * invn - mu * mu;
  float y = (hh[(size_t)b * 128 + c] - mu) * rsqrtf(var + 1e-5f) * g[c] + bbn[c];
  y = (y > 0.f) ? y : 0.01f * y;
  float p = y * Wh2[c];
  for (int o = 32; o; o >>= 1) p += __shfl_down(p, o);
  if ((threadIdx.x & 63) == 0) red[threadIdx.x >> 6] = p;
  __syncthreads();
  if (threadIdx.x == 0) out[(size_t)b * 2 + t] = red[0] + red[1] + bh2[0];
}

extern "C" void kernel_launch(void* const* d_in, const int* in_sizes, int n_in,
                              void* d_out, int out_size, void* d_ws, size_t ws_size,
                              hipStream_t stream) {
  (void)n_in; (void)ws_size;
  const float* x     = (const float*)d_in[0];
  const int*   eidx  = (const int*)d_in[1];
  const float* eattr = (const float*)d_in[2];
  const int*   batch = (const int*)d_in[3];
  const float* eW1   = (const float*)d_in[4];
  const float* ea_s1 = (const float*)d_in[5];
  const float* ea_d1 = (const float*)d_in[6];
  const float* eWe1  = (const float*)d_in[7];
  const float* ea_e1 = (const float*)d_in[8];
  const float* eb1   = (const float*)d_in[9];
  const float* bn1_g = (const float*)d_in[10];
  const float* bn1_b = (const float*)d_in[11];
  const float* eW2   = (const float*)d_in[12];
  const float* ea_s2 = (const float*)d_in[13];
  const float* ea_d2 = (const float*)d_in[14];
  const float* eWe2  = (const float*)d_in[15];
  const float* ea_e2 = (const float*)d_in[16];
  const float* eb2   = (const float*)d_in[17];
  const float* bn2_g = (const float*)d_in[18];
  const float* bn2_b = (const float*)d_in[19];
  const float* gW    = (const float*)d_in[20];
  const float* ga_s  = (const float*)d_in[21];
  const float* ga_d  = (const float*)d_in[22];
  const float* gWe   = (const float*)d_in[23];
  const float* ga_e  = (const float*)d_in[24];
  const float* gb    = (const float*)d_in[25];
  const float* Wq    = (const float*)d_in[26];
  const float* Wk    = (const float*)d_in[27];
  const float* Wv    = (const float*)d_in[28];
  const float* pe    = (const float*)d_in[29];
  const float* Wh1   = (const float*)d_in[30];
  const float* bh1   = (const float*)d_in[31];
  const float* hbn_g = (const float*)d_in[32];
  const float* hbn_b = (const float*)d_in[33];
  const float* Wh2   = (const float*)d_in[34];
  const float* bh2   = (const float*)d_in[35];
  float* out = (float*)d_out;

  const int n = in_sizes[0] / DIN;    // 200000
  const int e = in_sizes[1] / 2;      // 800000
  const int nb_graphs = out_size / 2; // 4096
  const int* src = eidx;
  const int* dst = eidx + e;

  char* p = (char*)d_ws;
  auto carve = [&](size_t bytes) {
    void* r = (void*)p;
    p += (bytes + 255) & ~(size_t)255;
    return r;
  };
  int* deg       = (int*)carve((size_t)n * 4);
  int* off       = (int*)carve(((size_t)n + 1) * 4);
  int* cursor    = (int*)carve((size_t)n * 4);
  int* eid       = (int*)carve((size_t)e * 4);
  int* bsum      = (int*)carve(4096);
  int* src_csr   = (int*)carve((size_t)e * 4);
  int* dst_csr   = (int*)carve((size_t)e * 4);
  float* edots   = (float*)carve((size_t)14 * e * 4);
  float* weall   = (float*)carve(14 * 16 * 4);
  float* s_arr   = (float*)carve((size_t)n * 4);
  float* d_arr   = (float*)carve((size_t)n * 4);
  float* lcsr    = (float*)carve((size_t)e * 4);
  float* sums    = (float*)carve(256 * 4);
  float* gates0  = (float*)carve((size_t)n * 16);
  float* gates1  = (float*)carve((size_t)n * 16);
  float* gfeat   = (float*)carve((size_t)n * 16);
  float* pooled0 = (float*)carve((size_t)nb_graphs * H * 4);
  float* pooled1 = (float*)carve((size_t)nb_graphs * H * 4);
  float* Ktbuf   = (float*)carve((size_t)L * H * 4);
  float* Vbuf    = (float*)carve((size_t)L * H * 4);
  float* Qbuf    = (float*)carve((size_t)nb_graphs * H * 4);
  float* ctxb    = (float*)carve((size_t)nb_graphs * H * 4);
  float* hhb     = (float*)carve((size_t)nb_graphs * H * 4);
  bf16* featbuf  = (bf16*)carve((size_t)n * H * 2);
  bf16* buf1     = (bf16*)carve((size_t)n * H * 2);
  bf16* xbf      = (bf16*)carve((size_t)n * DIN * 2);
  bf16* Wp1      = (bf16*)carve((size_t)6 * 8192 * 2);
  bf16* Wp2      = (bf16*)carve((size_t)6 * 16384 * 2);

  float invn = 1.0f / n;

  // ---- one-time prep: x->bf16, weight repack
  k_cvt_bf16<<<(n * DIN / 2 + 255) / 256, 256, 0, stream>>>(x, xbf, n * DIN / 2);
  k_wpackall<<<(6 * 8192 + 6 * 16384 + 255) / 256, 256, 0, stream>>>(eW1, eW2, Wp1, Wp2);

  // ---- CSR by dst (reused by all 14 GAT convs)
  k_zero_i32<<<(n + 255) / 256, 256, 0, stream>>>(deg, n);
  k_deg<<<(e + 255) / 256, 256, 0, stream>>>(dst, deg, e);
  int nsb = (n + 511) / 512;
  k_scan1<<<nsb, 512, 0, stream>>>(deg, off, bsum, n);
  k_scan2<<<1, 512, 0, stream>>>(bsum, nsb);
  k_scan3<<<nsb, 512, 0, stream>>>(off, bsum, cursor, n, e);
  k_fill<<<(e + 255) / 256, 256, 0, stream>>>(dst, cursor, eid, e);

  // ---- all 14 edge-weight dots in CSR order
  k_weall<<<1, 256, 0, stream>>>(gWe, ga_e, eWe1, ea_e1, eWe2, ea_e2, weall);
  k_csrprep<<<(e + 255) / 256, 256, 0, stream>>>(eid, src, dst, eattr, weall, src_csr,
                                                 dst_csr, edots, e);

  // ---- gates (2 tasks)
  for (int t = 0; t < 2; ++t) {
    float* gates = t ? gates1 : gates0;
    k_gfeat<<<(n + 255) / 256, 256, 0, stream>>>(x, gW + t * DIN * 4, ga_s + t * 4,
                                                 ga_d + t * 4, gfeat, s_arr, d_arr, n);
    k_edge_l<<<(e + 255) / 256, 256, 0, stream>>>(src_csr, dst_csr, edots + (size_t)t * e,
                                                  s_arr, d_arr, lcsr, e);
    k_agg4<<<(n + 255) / 256, 256, 0, stream>>>(off, src_csr, lcsr, gfeat, gb + t * 4,
                                                gates, n);
  }

  // ---- zero pooled accumulators
  k_zero_f32<<<(nb_graphs * H + 255) / 256, 256, 0, stream>>>(pooled0, nb_graphs * H);
  k_zero_f32<<<(nb_graphs * H + 255) / 256, 256, 0, stream>>>(pooled1, nb_graphs * H);

  // ---- 6 experts (MFMA GEMMs with fused s/d), fused BN2+gate+pool epilogue
  int nquads = n * 32;
  int gblk = (n + 63) / 64;
  for (int i = 0; i < 6; ++i) {
    // layer 1 (DIN -> H)
    k_mfma_gemm<DIN><<<gblk, 256, 0, stream>>>(xbf, Wp1 + (size_t)i * 8192,
                                               ea_s1 + i * H, ea_d1 + i * H, featbuf,
                                               s_arr, d_arr, n);
    k_edge_l<<<(e + 255) / 256, 256, 0, stream>>>(src_csr, dst_csr,
                                                  edots + (size_t)(2 + i) * e, s_arr,
                                                  d_arr, lcsr, e);
    k_agg128<<<(n + 7) / 8, 256, 0, stream>>>(off, src_csr, lcsr, featbuf, eb1 + i * H,
                                              buf1, n);
    k_zero_f32<<<1, 256, 0, stream>>>(sums, 256);
    k_bnstats_bf<<<1024, 256, 0, stream>>>(buf1, sums, sums + 128, n);
    k_bnapply_bf<<<(nquads + 255) / 256, 256, 0, stream>>>(buf1, sums, sums + 128,
                                                           bn1_g + i * H, bn1_b + i * H,
                                                           nquads, invn);
    // layer 2 (H -> H)
    k_mfma_gemm<H><<<gblk, 256, 0, stream>>>(buf1, Wp2 + (size_t)i * 16384,
                                             ea_s2 + i * H, ea_d2 + i * H, featbuf,
                                             s_arr, d_arr, n);
    k_edge_l<<<(e + 255) / 256, 256, 0, stream>>>(src_csr, dst_csr,
                                                  edots + (size_t)(8 + i) * e, s_arr,
                                                  d_arr, lcsr, e);
    k_agg128<<<(n + 7) / 8, 256, 0, stream>>>(off, src_csr, lcsr, featbuf, eb2 + i * H,
                                              buf1, n);
    k_zero_f32<<<1, 256, 0, stream>>>(sums, 256);
    k_bnstats_bf<<<1024, 256, 0, stream>>>(buf1, sums, sums + 128, n);
    int s0 = (i < 4) ? i : -1;
    int s1 = (i < 2) ? i : (i >= 4 ? i - 2 : -1);
    k_poolexpert<<<nb_graphs, 64, 0, stream>>>(buf1, sums, sums + 128, bn2_g + i * H,
                                               bn2_b + i * H, batch, gates0, s0, gates1,
                                               s1, pooled0, pooled1, n, invn);
  }

  // ---- heads
  for (int t = 0; t < 2; ++t) {
    const float* pooled = t ? pooled1 : pooled0;
    k_kv<<<L, 128, 0, stream>>>(pe + (size_t)t * L * PD, Wk + t * PD * H, Wv + t * PD * H,
                                Ktbuf, Vbuf);
    k_rowgemm<<<nb_graphs, 128, 0, stream>>>(pooled, Wq + t * H * H, Qbuf, H);
    k_attn<<<nb_graphs / 4, 128, 0, stream>>>(Qbuf, Ktbuf, Vbuf, ctxb);
    k_head1<<<nb_graphs, 128, 0, stream>>>(pooled, ctxb, Wh1 + t * 2 * H * H, bh1 + t * H,
                                           hhb);
    k_zero_f32<<<1, 256, 0, stream>>>(sums, 256);
    k_bnstats_f32<<<256, 256, 0, stream>>>(hhb, sums, sums + 128, nb_graphs);
    k_head2<<<nb_graphs, 128, 0, stream>>>(hhb, sums, sums + 128, hbn_g + t * H,
                                           hbn_b + t * H, Wh2 + t * H, bh2 + t, out, t,
                                           1.0f / nb_graphs);
  }
}

// Round 5
// 2795.071 us; speedup vs baseline: 2.2631x; 1.3747x over previous
//
#include <hip/hip_runtime.h>
#include <hip/hip_bf16.h>
#include <cstdint>
#include <cstddef>
#include <type_traits>

constexpr int DIN = 64;
constexpr int DE  = 16;
constexpr int H   = 128;
constexpr int L   = 512;
constexpr int PD  = 1152;
constexpr int NBSTAT = 2048;  // stage-1 blocks for BN stats

using bf16 = __hip_bfloat16;
typedef __attribute__((ext_vector_type(8))) short short8;
typedef __attribute__((ext_vector_type(4))) float float4v;

// ---- bf16 pack/unpack helpers (bf16x2 in a uint) ----
__device__ __forceinline__ float bflo(unsigned u) { return __uint_as_float(u << 16); }
__device__ __forceinline__ float bfhi(unsigned u) { return __uint_as_float(u & 0xffff0000u); }
__device__ __forceinline__ unsigned short f2b(float f) {
  bf16 h = __float2bfloat16(f);
  return *reinterpret_cast<unsigned short*>(&h);
}
__device__ __forceinline__ unsigned pack2(float a, float b) {
  return (unsigned)f2b(a) | ((unsigned)f2b(b) << 16);
}

// ---------------------------------------------------------------- zero fill
__global__ void k_zero_i32(int* p, int n) {
  int i = blockIdx.x * 256 + threadIdx.x;
  if (i < n) p[i] = 0;
}
__global__ void k_zero_f32(float* p, int n) {
  int i = blockIdx.x * 256 + threadIdx.x;
  if (i < n) p[i] = 0.f;
}

// fp32 -> bf16 (2 elements per thread)
__global__ void k_cvt_bf16(const float* __restrict__ in, bf16* __restrict__ out, int npairs) {
  int i = blockIdx.x * 256 + threadIdx.x;
  if (i >= npairs) return;
  float2 v = ((const float2*)in)[i];
  ((unsigned*)out)[i] = pack2(v.x, v.y);
}

// ---------------------------------------------------------------- CSR build
__global__ void k_deg(const int* __restrict__ dst, int* __restrict__ deg, int e) {
  int i = blockIdx.x * 256 + threadIdx.x;
  if (i < e) atomicAdd(&deg[dst[i]], 1);
}

__global__ void k_scan1(const int* __restrict__ deg, int* __restrict__ out,
                        int* __restrict__ bsum, int n) {
  __shared__ int tmp[512];
  int tid = threadIdx.x;
  int i = blockIdx.x * 512 + tid;
  int v = (i < n) ? deg[i] : 0;
  tmp[tid] = v; __syncthreads();
  for (int s = 1; s < 512; s <<= 1) {
    int t = (tid >= s) ? tmp[tid - s] : 0;
    __syncthreads();
    tmp[tid] += t;
    __syncthreads();
  }
  if (i < n) out[i] = tmp[tid] - v;
  if (tid == 511) bsum[blockIdx.x] = tmp[511];
}

__global__ void k_scan2(int* bsum, int nb) {  // nb <= 512
  __shared__ int tmp[512];
  int tid = threadIdx.x;
  int v = (tid < nb) ? bsum[tid] : 0;
  tmp[tid] = v; __syncthreads();
  for (int s = 1; s < 512; s <<= 1) {
    int t = (tid >= s) ? tmp[tid - s] : 0;
    __syncthreads();
    tmp[tid] += t;
    __syncthreads();
  }
  if (tid < nb) bsum[tid] = tmp[tid] - v;
}

__global__ void k_scan3(int* __restrict__ off, const int* __restrict__ bsum,
                        int* __restrict__ cursor, int n, int total) {
  int i = blockIdx.x * 512 + threadIdx.x;
  if (i < n) { int v = off[i] + bsum[blockIdx.x]; off[i] = v; cursor[i] = v; }
  if (i == 0) off[n] = total;
}

__global__ void k_fill(const int* __restrict__ dst, int* __restrict__ cursor,
                       int* __restrict__ eid, int e) {
  int i = blockIdx.x * 256 + threadIdx.x;
  if (i < e) { int slot = atomicAdd(&cursor[dst[i]], 1); eid[slot] = i; }
}

// ---------------------------------------------------------------- weall: all 14 conv edge-weight vectors [14][16]
__global__ void k_weall(const float* __restrict__ gWe, const float* __restrict__ ga_e,
                        const float* __restrict__ eWe1, const float* __restrict__ ea_e1,
                        const float* __restrict__ eWe2, const float* __restrict__ ea_e2,
                        float* __restrict__ weall) {
  int tid = threadIdx.x;
  if (tid >= 14 * 16) return;
  int c = tid >> 4, j = tid & 15;
  float acc = 0.f;
  if (c < 2) {
    for (int k = 0; k < 4; ++k) acc += gWe[(c * 16 + j) * 4 + k] * ga_e[c * 4 + k];
  } else if (c < 8) {
    int i = c - 2;
    for (int k = 0; k < 128; ++k) acc += eWe1[(i * 16 + j) * 128 + k] * ea_e1[i * 128 + k];
  } else {
    int i = c - 8;
    for (int k = 0; k < 128; ++k) acc += eWe2[(i * 16 + j) * 128 + k] * ea_e2[i * 128 + k];
  }
  weall[c * 16 + j] = acc;
}

// ---------------------------------------------------------------- weight repack into MFMA B-frag order (bf16)
__global__ void k_wpackall(const float* __restrict__ eW1, const float* __restrict__ eW2,
                           bf16* __restrict__ Wp1, bf16* __restrict__ Wp2) {
  int tid = blockIdx.x * 256 + threadIdx.x;
  const int L1TOT = 6 * 8192;
  if (tid < L1TOT) {
    int i = tid / 8192, r = tid % 8192;
    int kt = r / 4096, nt = (r / 512) & 7, l = (r / 8) & 63, j = r & 7;
    int k = kt * 32 + (l >> 4) * 8 + j, col = nt * 16 + (l & 15);
    Wp1[tid] = __float2bfloat16(eW1[(size_t)i * 64 * 128 + k * 128 + col]);
  } else {
    int t2 = tid - L1TOT;
    if (t2 >= 6 * 16384) return;
    int i = t2 / 16384, r = t2 % 16384;
    int kt = r / 4096, nt = (r / 512) & 7, l = (r / 8) & 63, j = r & 7;
    int k = kt * 32 + (l >> 4) * 8 + j, col = nt * 16 + (l & 15);
    Wp2[t2] = __float2bfloat16(eW2[(size_t)i * 128 * 128 + k * 128 + col]);
  }
}

// ---------------------------------------------------------------- CSR prep: src/dst in CSR order + all 14 edots
__global__ void k_csrprep(const int* __restrict__ eid, const int* __restrict__ src,
                          const int* __restrict__ dst, const float* __restrict__ eattr,
                          const float* __restrict__ weall, int* __restrict__ src_csr,
                          int* __restrict__ dst_csr, float* __restrict__ edots, int e) {
  __shared__ float w[14 * 16];
  if (threadIdx.x < 14 * 16) w[threadIdx.x] = weall[threadIdx.x];
  __syncthreads();
  int i = blockIdx.x * 256 + threadIdx.x;
  if (i >= e) return;
  int ed = eid[i];
  src_csr[i] = src[ed];
  dst_csr[i] = dst[ed];
  float ea[16];
  const float4* ep = (const float4*)(eattr + (size_t)ed * 16);
#pragma unroll
  for (int q = 0; q < 4; ++q) {
    float4 v = ep[q];
    ea[q * 4] = v.x; ea[q * 4 + 1] = v.y; ea[q * 4 + 2] = v.z; ea[q * 4 + 3] = v.w;
  }
#pragma unroll
  for (int c = 0; c < 14; ++c) {
    float acc = 0.f;
#pragma unroll
    for (int j = 0; j < 16; ++j) acc += ea[j] * w[c * 16 + j];
    edots[(size_t)c * e + i] = acc;
  }
}

// ---------------------------------------------------------------- MFMA GEMM: out[N,128](bf16) = A[N,K](bf16) @ W(packed)
// BN=true: apply BN1(scale/shift from partial-reduced stats) + leaky(0.01) to A during staging.
// Also fuses s[n] = out_row . a_s, d[n] = out_row . a_d
template <int K, bool BN>
__global__ __launch_bounds__(256) void k_mfma_gemm(
    const bf16* __restrict__ A, const bf16* __restrict__ Wp,
    const float* __restrict__ a_s, const float* __restrict__ a_d,
    bf16* __restrict__ out, float* __restrict__ s, float* __restrict__ d, int n,
    const float* __restrict__ bnsums, const float* __restrict__ bng,
    const float* __restrict__ bnb, float invn) {
  constexpr int KT = K / 32;
  __shared__ bf16 At[64][K + 8];
  __shared__ float sscale[128], sshift[128];
  if (BN) {
    if (threadIdx.x < K) {
      int c = threadIdx.x;
      float mu = bnsums[c] * invn;
      float var = bnsums[128 + c] * invn - mu * mu;
      float sc = rsqrtf(var + 1e-5f) * bng[c];
      sscale[c] = sc;
      sshift[c] = bnb[c] - mu * sc;
    }
    __syncthreads();
  }
  int row0 = blockIdx.x * 64;
  const int vecPerRow = K / 8;
  for (int idx = threadIdx.x; idx < 64 * vecPerRow; idx += 256) {
    int r = idx / vecPerRow, v = idx - r * vecPerRow;
    int gr = row0 + r;
    uint4 u = {0u, 0u, 0u, 0u};
    if (gr < n) u = ((const uint4*)(A + (size_t)gr * K))[v];
    if (BN) {
      float f[8] = {bflo(u.x), bfhi(u.x), bflo(u.y), bfhi(u.y),
                    bflo(u.z), bfhi(u.z), bflo(u.w), bfhi(u.w)};
      int c0 = v * 8;
#pragma unroll
      for (int j = 0; j < 8; ++j) {
        float y = f[j] * sscale[c0 + j] + sshift[c0 + j];
        f[j] = (y > 0.f) ? y : 0.01f * y;
      }
      u.x = pack2(f[0], f[1]); u.y = pack2(f[2], f[3]);
      u.z = pack2(f[4], f[5]); u.w = pack2(f[6], f[7]);
    }
    *((uint4*)&At[r][v * 8]) = u;
  }
  __syncthreads();
  int lane = threadIdx.x & 63, w = threadIdx.x >> 6;
  int c = lane & 15, q = lane >> 4;
  int wrow = w * 16;
  short8 afrag[KT];
#pragma unroll
  for (int kt = 0; kt < KT; ++kt)
    afrag[kt] = *(const short8*)&At[wrow + c][kt * 32 + q * 8];
  const short8* wp8 = (const short8*)Wp;
  float4v acc[8];
#pragma unroll
  for (int nt = 0; nt < 8; ++nt) acc[nt] = {0.f, 0.f, 0.f, 0.f};
#pragma unroll
  for (int kt = 0; kt < KT; ++kt) {
#pragma unroll
    for (int nt = 0; nt < 8; ++nt) {
      short8 bfrag = wp8[(kt * 8 + nt) * 64 + lane];
      acc[nt] = __builtin_amdgcn_mfma_f32_16x16x32_bf16(afrag[kt], bfrag, acc[nt], 0, 0, 0);
    }
  }
#pragma unroll
  for (int nt = 0; nt < 8; ++nt) {
#pragma unroll
    for (int reg = 0; reg < 4; ++reg) {
      int gr = row0 + wrow + q * 4 + reg;
      if (gr < n) out[(size_t)gr * 128 + nt * 16 + c] = __float2bfloat16(acc[nt][reg]);
    }
  }
#pragma unroll
  for (int reg = 0; reg < 4; ++reg) {
    float vs = 0.f, vd = 0.f;
#pragma unroll
    for (int nt = 0; nt < 8; ++nt) {
      float y = acc[nt][reg];
      int col = nt * 16 + c;
      vs += y * a_s[col];
      vd += y * a_d[col];
    }
#pragma unroll
    for (int o = 1; o < 16; o <<= 1) { vs += __shfl_xor(vs, o); vd += __shfl_xor(vd, o); }
    int gr = row0 + wrow + q * 4 + reg;
    if (c == 0 && gr < n) { s[gr] = vs; d[gr] = vd; }
  }
}

// ---------------------------------------------------------------- edge logits in CSR order
__global__ void k_edge_l(const int* __restrict__ src_csr, const int* __restrict__ dst_csr,
                         const float* __restrict__ edot, const float* __restrict__ s,
                         const float* __restrict__ d, float* __restrict__ lcsr, int e) {
  int i = blockIdx.x * 256 + threadIdx.x;
  if (i >= e) return;
  float l = s[src_csr[i]] + d[dst_csr[i]] + edot[i];
  lcsr[i] = (l > 0.f) ? l : 0.2f * l;
}

// ---------------------------------------------------------------- agg: softmax over incoming + gather (32 lanes/node)
__global__ void k_agg128(const int* __restrict__ off, const int* __restrict__ src_csr,
                         const float* __restrict__ lcsr, const bf16* __restrict__ feat,
                         const float* __restrict__ bias, bf16* __restrict__ out, int n) {
  int node = blockIdx.x * 8 + (threadIdx.x >> 5);
  int lane = threadIdx.x & 31;
  if (node >= n) return;
  int e0 = off[node], e1 = off[node + 1];
  float m = -INFINITY;
  for (int i = e0 + lane; i < e1; i += 32) m = fmaxf(m, lcsr[i]);
  for (int o = 16; o; o >>= 1) m = fmaxf(m, __shfl_xor(m, o));
  float den = 0.f;
  for (int i = e0 + lane; i < e1; i += 32) den += __expf(lcsr[i] - m);
  for (int o = 16; o; o >>= 1) den += __shfl_xor(den, o);
  float inv = 1.0f / (den + 1e-16f);
  float4 acc = {0.f, 0.f, 0.f, 0.f};
  for (int i = e0; i < e1; ++i) {
    float alpha = __expf(lcsr[i] - m) * inv;
    const uint2* fr = (const uint2*)(feat + (size_t)src_csr[i] * 128);
    uint2 u = fr[lane];
    acc.x += alpha * bflo(u.x);
    acc.y += alpha * bfhi(u.x);
    acc.z += alpha * bflo(u.y);
    acc.w += alpha * bfhi(u.y);
  }
  float4 b4 = ((const float4*)bias)[lane];
  uint2 o2;
  o2.x = pack2(acc.x + b4.x, acc.y + b4.y);
  o2.y = pack2(acc.z + b4.z, acc.w + b4.w);
  ((uint2*)(out + (size_t)node * 128))[lane] = o2;
}

// ---------------------------------------------------------------- gate feature + s/d
__global__ void k_gfeat(const float* __restrict__ x, const float* __restrict__ W,
                        const float* __restrict__ a_s, const float* __restrict__ a_d,
                        float* __restrict__ gfeat, float* __restrict__ s,
                        float* __restrict__ d, int n) {
  int i = blockIdx.x * 256 + threadIdx.x;
  if (i >= n) return;
  const float* xr = x + (size_t)i * DIN;
  float acc[4] = {0.f, 0.f, 0.f, 0.f};
  for (int k = 0; k < DIN; ++k) {
    float xv = xr[k];
#pragma unroll
    for (int j = 0; j < 4; ++j) acc[j] += xv * W[k * 4 + j];
  }
  float ss = 0.f, dd = 0.f;
#pragma unroll
  for (int j = 0; j < 4; ++j) {
    gfeat[(size_t)i * 4 + j] = acc[j];
    ss += acc[j] * a_s[j];
    dd += acc[j] * a_d[j];
  }
  s[i] = ss; d[i] = dd;
}

// ---------------------------------------------------------------- gate aggregation + channel softmax
__global__ void k_agg4(const int* __restrict__ off, const int* __restrict__ src_csr,
                       const float* __restrict__ lcsr, const float* __restrict__ gfeat,
                       const float* __restrict__ bias, float* __restrict__ gates, int n) {
  int node = blockIdx.x * 256 + threadIdx.x;
  if (node >= n) return;
  int e0 = off[node], e1 = off[node + 1];
  float m = -INFINITY;
  for (int i = e0; i < e1; ++i) m = fmaxf(m, lcsr[i]);
  float den = 0.f;
  for (int i = e0; i < e1; ++i) den += __expf(lcsr[i] - m);
  float inv = 1.f / (den + 1e-16f);
  float4 acc = {0.f, 0.f, 0.f, 0.f};
  for (int i = e0; i < e1; ++i) {
    float a = __expf(lcsr[i] - m) * inv;
    float4 fr = *((const float4*)(gfeat + (size_t)src_csr[i] * 4));
    acc.x += a * fr.x; acc.y += a * fr.y; acc.z += a * fr.z; acc.w += a * fr.w;
  }
  float b0 = bias[0], b1 = bias[1], b2 = bias[2], b3 = bias[3];
  acc.x += b0; acc.y += b1; acc.z += b2; acc.w += b3;
  float mm = fmaxf(fmaxf(acc.x, acc.y), fmaxf(acc.z, acc.w));
  float e0s = __expf(acc.x - mm), e1s = __expf(acc.y - mm);
  float e2s = __expf(acc.z - mm), e3s = __expf(acc.w - mm);
  float is = 1.f / (e0s + e1s + e2s + e3s);
  float4 g4 = {e0s * is, e1s * is, e2s * is, e3s * is};
  *((float4*)(gates + (size_t)node * 4)) = g4;
}

// ---------------------------------------------------------------- BN stats stage 1: per-block partials (no atomics)
// partials[b][0..127] = sum, partials[b][128..255] = sumsq
__global__ __launch_bounds__(256) void k_bnstats_part(const bf16* __restrict__ x,
                                                      float* __restrict__ partials, int n) {
  __shared__ float sm[16 * 128];
  __shared__ float sq[16 * 128];
  int t = threadIdx.x;
  int g = t & 15;     // channel group: ch 8g..8g+7
  int slot = t >> 4;  // row slot 0..15
  float s[8], q[8];
#pragma unroll
  for (int j = 0; j < 8; ++j) { s[j] = 0.f; q[j] = 0.f; }
  for (int r = blockIdx.x * 16 + slot; r < n; r += gridDim.x * 16) {
    uint4 u = ((const uint4*)(x + (size_t)r * 128))[g];
    float f[8] = {bflo(u.x), bfhi(u.x), bflo(u.y), bfhi(u.y),
                  bflo(u.z), bfhi(u.z), bflo(u.w), bfhi(u.w)};
#pragma unroll
    for (int j = 0; j < 8; ++j) { s[j] += f[j]; q[j] += f[j] * f[j]; }
  }
#pragma unroll
  for (int j = 0; j < 8; ++j) {
    sm[slot * 128 + g * 8 + j] = s[j];
    sq[slot * 128 + g * 8 + j] = q[j];
  }
  __syncthreads();
  if (t < 128) {
    float a = 0.f, b = 0.f;
#pragma unroll
    for (int sl = 0; sl < 16; ++sl) { a += sm[sl * 128 + t]; b += sq[sl * 128 + t]; }
    partials[(size_t)blockIdx.x * 256 + t] = a;
    partials[(size_t)blockIdx.x * 256 + 128 + t] = b;
  }
}

// stage 2: reduce partials -> sums[0..127], sums[128..255]. grid = 16 blocks x 8 ch.
__global__ void k_bnstats_fin(const float* __restrict__ partials, float* __restrict__ sums,
                              int nblk) {
  int t = threadIdx.x;
  int cl = t >> 5, sl = t & 31;
  int ch = blockIdx.x * 8 + cl;
  float a = 0.f, b = 0.f;
  for (int blk = sl; blk < nblk; blk += 32) {
    a += partials[(size_t)blk * 256 + ch];
    b += partials[(size_t)blk * 256 + 128 + ch];
  }
#pragma unroll
  for (int o = 16; o; o >>= 1) { a += __shfl_xor(a, o); b += __shfl_xor(b, o); }
  if (sl == 0) { sums[ch] = a; sums[128 + ch] = b; }
}

// BN stats fp32 (head path, tiny)
__global__ void k_bnstats_f32(const float* __restrict__ x, float* __restrict__ sums,
                              float* __restrict__ sumsq, int n) {
  __shared__ float s1[256], s2[256];
  int c = threadIdx.x & 127, half = threadIdx.x >> 7;
  float a = 0.f, b = 0.f;
  for (int r = blockIdx.x * 2 + half; r < n; r += gridDim.x * 2) {
    float v = x[(size_t)r * 128 + c];
    a += v; b += v * v;
  }
  s1[threadIdx.x] = a; s2[threadIdx.x] = b;
  __syncthreads();
  if (half == 0) {
    atomicAdd(&sums[c], s1[c] + s1[c + 128]);
    atomicAdd(&sumsq[c], s2[c] + s2[c + 128]);
  }
}

// ---------------------------------------------------------------- fused BN2+leaky+gate+pool
__global__ void k_poolexpert(const bf16* __restrict__ x, const float* __restrict__ sums,
                             const float* __restrict__ sumsq, const float* __restrict__ g,
                             const float* __restrict__ bb, const int* __restrict__ batch,
                             const float* __restrict__ gates0, int slot0,
                             const float* __restrict__ gates1, int slot1,
                             float* __restrict__ pooled0, float* __restrict__ pooled1,
                             int n, float invn) {
  int b = blockIdx.x, t = threadIdx.x;
  int lo = 0, hi = n;
  while (lo < hi) { int m = (lo + hi) >> 1; if (batch[m] < b) lo = m + 1; else hi = m; }
  int start = lo;
  lo = start; hi = n;
  while (lo < hi) { int m = (lo + hi) >> 1; if (batch[m] < b + 1) lo = m + 1; else hi = m; }
  int end = lo;
  int c0 = 2 * t, c1 = 2 * t + 1;
  float mu0 = sums[c0] * invn, mu1 = sums[c1] * invn;
  float sc0 = rsqrtf(sumsq[c0] * invn - mu0 * mu0 + 1e-5f) * g[c0];
  float sc1 = rsqrtf(sumsq[c1] * invn - mu1 * mu1 + 1e-5f) * g[c1];
  float sh0 = bb[c0], sh1 = bb[c1];
  float a00 = 0.f, a01 = 0.f, a10 = 0.f, a11 = 0.f;
  for (int r = start; r < end; ++r) {
    unsigned u = ((const unsigned*)(x + (size_t)r * 128))[t];
    float y0 = (bflo(u) - mu0) * sc0 + sh0;
    float y1 = (bfhi(u) - mu1) * sc1 + sh1;
    y0 = (y0 > 0.f) ? y0 : 0.01f * y0;
    y1 = (y1 > 0.f) ? y1 : 0.01f * y1;
    if (slot0 >= 0) {
      float gw = gates0[(size_t)r * 4 + slot0];
      a00 += gw * y0; a01 += gw * y1;
    }
    if (slot1 >= 0) {
      float gw = gates1[(size_t)r * 4 + slot1];
      a10 += gw * y0; a11 += gw * y1;
    }
  }
  if (slot0 >= 0) {
    pooled0[(size_t)b * 128 + c0] += a00;
    pooled0[(size_t)b * 128 + c1] += a01;
  }
  if (slot1 >= 0) {
    pooled1[(size_t)b * 128 + c0] += a10;
    pooled1[(size_t)b * 128 + c1] += a11;
  }
}

// ---------------------------------------------------------------- K^T = (pe@Wk)^T [128][L], V = pe@Wv [L][128]
__global__ void k_kv(const float* __restrict__ pe, const float* __restrict__ Wk,
                     const float* __restrict__ Wv, float* __restrict__ Kt,
                     float* __restrict__ Vout) {
  __shared__ float per[PD];
  int l = blockIdx.x, c = threadIdx.x;
  for (int p = threadIdx.x; p < PD; p += 128) per[p] = pe[(size_t)l * PD + p];
  __syncthreads();
  float ak = 0.f, av = 0.f;
  for (int p = 0; p < PD; ++p) {
    float v = per[p];
    ak += v * Wk[p * 128 + c];
    av += v * Wv[p * 128 + c];
  }
  Kt[(size_t)c * L + l] = ak;
  Vout[(size_t)l * 128 + c] = av;
}

// out[row,:] = in[row,:Kdim] @ W[Kdim,128]
__global__ void k_rowgemm(const float* __restrict__ in, const float* __restrict__ W,
                          float* __restrict__ out, int Kdim) {
  __shared__ float rr[256];
  int row = blockIdx.x, c = threadIdx.x;
  for (int k = threadIdx.x; k < Kdim; k += 128) rr[k] = in[(size_t)row * Kdim + k];
  __syncthreads();
  float acc = 0.f;
  for (int k = 0; k < Kdim; ++k) acc += rr[k] * W[k * 128 + c];
  out[(size_t)row * 128 + c] = acc;
}

// ---------------------------------------------------------------- cross-attention, 4 graphs per block
__global__ void k_attn(const float* __restrict__ Q, const float* __restrict__ Kt,
                       const float* __restrict__ Vm, float* __restrict__ ctx) {
  __shared__ float q[4][128];
  __shared__ float sc[4][L];
  __shared__ float4 red[128];
  __shared__ float4 Mg, Ig;
  int b0 = blockIdx.x * 4, t = threadIdx.x;
#pragma unroll
  for (int g = 0; g < 4; ++g) q[g][t] = Q[(size_t)(b0 + g) * 128 + t];
  __syncthreads();
  float acc[4][4];
#pragma unroll
  for (int g = 0; g < 4; ++g)
#pragma unroll
    for (int j = 0; j < 4; ++j) acc[g][j] = 0.f;
  for (int k = 0; k < 128; ++k) {
    const float* kr = Kt + (size_t)k * L + t;
    float k0 = kr[0], k1 = kr[128], k2 = kr[256], k3 = kr[384];
#pragma unroll
    for (int g = 0; g < 4; ++g) {
      float qv = q[g][k];
      acc[g][0] += qv * k0; acc[g][1] += qv * k1;
      acc[g][2] += qv * k2; acc[g][3] += qv * k3;
    }
  }
  const float scale = 0.08838834764831845f;
  float4 pm;
  {
    float m[4];
#pragma unroll
    for (int g = 0; g < 4; ++g) {
#pragma unroll
      for (int j = 0; j < 4; ++j) {
        acc[g][j] *= scale;
        sc[g][t + j * 128] = acc[g][j];
      }
      m[g] = fmaxf(fmaxf(acc[g][0], acc[g][1]), fmaxf(acc[g][2], acc[g][3]));
    }
    pm = {m[0], m[1], m[2], m[3]};
  }
  red[t] = pm; __syncthreads();
  for (int s = 64; s > 0; s >>= 1) {
    if (t < s) {
      float4 o = red[t + s];
      red[t].x = fmaxf(red[t].x, o.x); red[t].y = fmaxf(red[t].y, o.y);
      red[t].z = fmaxf(red[t].z, o.z); red[t].w = fmaxf(red[t].w, o.w);
    }
    __syncthreads();
  }
  if (t == 0) Mg = red[0];
  __syncthreads();
  float4 M = Mg;
  float4 ps = {0, 0, 0, 0};
#pragma unroll
  for (int g = 0; g < 4; ++g) {
    float mg = (g == 0) ? M.x : (g == 1) ? M.y : (g == 2) ? M.z : M.w;
    float sgsum = 0.f;
#pragma unroll
    for (int j = 0; j < 4; ++j) {
      float e = __expf(acc[g][j] - mg);
      sc[g][t + j * 128] = e;
      sgsum += e;
    }
    if (g == 0) ps.x = sgsum; else if (g == 1) ps.y = sgsum;
    else if (g == 2) ps.z = sgsum; else ps.w = sgsum;
  }
  __syncthreads();
  red[t] = ps; __syncthreads();
  for (int s = 64; s > 0; s >>= 1) {
    if (t < s) {
      float4 o = red[t + s];
      red[t].x += o.x; red[t].y += o.y; red[t].z += o.z; red[t].w += o.w;
    }
    __syncthreads();
  }
  if (t == 0) Ig = {1.f / red[0].x, 1.f / red[0].y, 1.f / red[0].z, 1.f / red[0].w};
  __syncthreads();
  float4 I = Ig;
  float o0 = 0.f, o1 = 0.f, o2 = 0.f, o3 = 0.f;
  for (int l = 0; l < L; ++l) {
    float v = Vm[(size_t)l * 128 + t];
    o0 += sc[0][l] * v; o1 += sc[1][l] * v; o2 += sc[2][l] * v; o3 += sc[3][l] * v;
  }
  ctx[(size_t)(b0 + 0) * 128 + t] = o0 * I.x;
  ctx[(size_t)(b0 + 1) * 128 + t] = o1 * I.y;
  ctx[(size_t)(b0 + 2) * 128 + t] = o2 * I.z;
  ctx[(size_t)(b0 + 3) * 128 + t] = o3 * I.w;
}

// hh = concat(pooled, ctx) @ Wh1 + bh1
__global__ void k_head1(const float* __restrict__ pooled, const float* __restrict__ ctx,
                        const float* __restrict__ Wh1, const float* __restrict__ bh1,
                        float* __restrict__ hh) {
  __shared__ float f[256];
  int b = blockIdx.x, c = threadIdx.x;
  f[c] = pooled[(size_t)b * 128 + c];
  f[c + 128] = ctx[(size_t)b * 128 + c];
  __syncthreads();
  float acc = bh1[c];
  for (int k = 0; k < 256; ++k) acc += f[k] * Wh1[k * 128 + c];
  hh[(size_t)b * 128 + c] = acc;
}

// bn + leaky + final dot with Wh2 -> out[b*2+t]
__global__ void k_head2(const float* __restrict__ hh, const float* __restrict__ sums,
                        const float* __restrict__ sumsq, const float* __restrict__ g,
                        const float* __restrict__ bbn, const float* __restrict__ Wh2,
                        const float* __restrict__ bh2, float* __restrict__ out, int t,
                        float invn) {
  __shared__ float red[2];
  int b = blockIdx.x, c = threadIdx.x;
  float mu = sums[c] * invn;
  float var = sumsq[c] * invn - mu * mu;
  float y = (hh[(size_t)b * 128 + c] - mu) * rsqrtf(var + 1e-5f) * g[c] + bbn[c];
  y = (y > 0.f) ? y : 0.01f * y;
  float p = y * Wh2[c];
  for (int o = 32; o; o >>= 1) p += __shfl_down(p, o);
  if ((threadIdx.x & 63) == 0) red[threadIdx.x >> 6] = p;
  __syncthreads();
  if (threadIdx.x == 0) out[(size_t)b * 2 + t] = red[0] + red[1] + bh2[0];
}

extern "C" void kernel_launch(void* const* d_in, const int* in_sizes, int n_in,
                              void* d_out, int out_size, void* d_ws, size_t ws_size,
                              hipStream_t stream) {
  (void)n_in; (void)ws_size;
  const float* x     = (const float*)d_in[0];
  const int*   eidx  = (const int*)d_in[1];
  const float* eattr = (const float*)d_in[2];
  const int*   batch = (const int*)d_in[3];
  const float* eW1   = (const float*)d_in[4];
  const float* ea_s1 = (const float*)d_in[5];
  const float* ea_d1 = (const float*)d_in[6];
  const float* eWe1  = (const float*)d_in[7];
  const float* ea_e1 = (const float*)d_in[8];
  const float* eb1   = (const float*)d_in[9];
  const float* bn1_g = (const float*)d_in[10];
  const float* bn1_b = (const float*)d_in[11];
  const float* eW2   = (const float*)d_in[12];
  const float* ea_s2 = (const float*)d_in[13];
  const float* ea_d2 = (const float*)d_in[14];
  const float* eWe2  = (const float*)d_in[15];
  const float* ea_e2 = (const float*)d_in[16];
  const float* eb2   = (const float*)d_in[17];
  const float* bn2_g = (const float*)d_in[18];
  const float* bn2_b = (const float*)d_in[19];
  const float* gW    = (const float*)d_in[20];
  const float* ga_s  = (const float*)d_in[21];
  const float* ga_d  = (const float*)d_in[22];
  const float* gWe   = (const float*)d_in[23];
  const float* ga_e  = (const float*)d_in[24];
  const float* gb    = (const float*)d_in[25];
  const float* Wq    = (const float*)d_in[26];
  const float* Wk    = (const float*)d_in[27];
  const float* Wv    = (const float*)d_in[28];
  const float* pe    = (const float*)d_in[29];
  const float* Wh1   = (const float*)d_in[30];
  const float* bh1   = (const float*)d_in[31];
  const float* hbn_g = (const float*)d_in[32];
  const float* hbn_b = (const float*)d_in[33];
  const float* Wh2   = (const float*)d_in[34];
  const float* bh2   = (const float*)d_in[35];
  float* out = (float*)d_out;

  const int n = in_sizes[0] / DIN;    // 200000
  const int e = in_sizes[1] / 2;      // 800000
  const int nb_graphs = out_size / 2; // 4096
  const int* src = eidx;
  const int* dst = eidx + e;

  char* p = (char*)d_ws;
  auto carve = [&](size_t bytes) {
    void* r = (void*)p;
    p += (bytes + 255) & ~(size_t)255;
    return r;
  };
  int* deg       = (int*)carve((size_t)n * 4);
  int* off       = (int*)carve(((size_t)n + 1) * 4);
  int* cursor    = (int*)carve((size_t)n * 4);
  int* eid       = (int*)carve((size_t)e * 4);
  int* bsum      = (int*)carve(4096);
  int* src_csr   = (int*)carve((size_t)e * 4);
  int* dst_csr   = (int*)carve((size_t)e * 4);
  float* edots   = (float*)carve((size_t)14 * e * 4);
  float* weall   = (float*)carve(14 * 16 * 4);
  float* s_arr   = (float*)carve((size_t)n * 4);
  float* d_arr   = (float*)carve((size_t)n * 4);
  float* lcsr    = (float*)carve((size_t)e * 4);
  float* sums    = (float*)carve(256 * 4);
  float* partials = (float*)carve((size_t)NBSTAT * 256 * 4);
  float* gates0  = (float*)carve((size_t)n * 16);
  float* gates1  = (float*)carve((size_t)n * 16);
  float* gfeat   = (float*)carve((size_t)n * 16);
  float* pooled0 = (float*)carve((size_t)nb_graphs * H * 4);
  float* pooled1 = (float*)carve((size_t)nb_graphs * H * 4);
  float* Ktbuf   = (float*)carve((size_t)L * H * 4);
  float* Vbuf    = (float*)carve((size_t)L * H * 4);
  float* Qbuf    = (float*)carve((size_t)nb_graphs * H * 4);
  float* ctxb    = (float*)carve((size_t)nb_graphs * H * 4);
  float* hhb     = (float*)carve((size_t)nb_graphs * H * 4);
  bf16* featbuf  = (bf16*)carve((size_t)n * H * 2);
  bf16* buf1     = (bf16*)carve((size_t)n * H * 2);
  bf16* xbf      = (bf16*)carve((size_t)n * DIN * 2);
  bf16* Wp1      = (bf16*)carve((size_t)6 * 8192 * 2);
  bf16* Wp2      = (bf16*)carve((size_t)6 * 16384 * 2);

  float invn = 1.0f / n;

  // ---- one-time prep: x->bf16, weight repack
  k_cvt_bf16<<<(n * DIN / 2 + 255) / 256, 256, 0, stream>>>(x, xbf, n * DIN / 2);
  k_wpackall<<<(6 * 8192 + 6 * 16384 + 255) / 256, 256, 0, stream>>>(eW1, eW2, Wp1, Wp2);

  // ---- CSR by dst (reused by all 14 GAT convs)
  k_zero_i32<<<(n + 255) / 256, 256, 0, stream>>>(deg, n);
  k_deg<<<(e + 255) / 256, 256, 0, stream>>>(dst, deg, e);
  int nsb = (n + 511) / 512;
  k_scan1<<<nsb, 512, 0, stream>>>(deg, off, bsum, n);
  k_scan2<<<1, 512, 0, stream>>>(bsum, nsb);
  k_scan3<<<nsb, 512, 0, stream>>>(off, bsum, cursor, n, e);
  k_fill<<<(e + 255) / 256, 256, 0, stream>>>(dst, cursor, eid, e);

  // ---- all 14 edge-weight dots in CSR order
  k_weall<<<1, 256, 0, stream>>>(gWe, ga_e, eWe1, ea_e1, eWe2, ea_e2, weall);
  k_csrprep<<<(e + 255) / 256, 256, 0, stream>>>(eid, src, dst, eattr, weall, src_csr,
                                                 dst_csr, edots, e);

  // ---- gates (2 tasks)
  for (int t = 0; t < 2; ++t) {
    float* gates = t ? gates1 : gates0;
    k_gfeat<<<(n + 255) / 256, 256, 0, stream>>>(x, gW + t * DIN * 4, ga_s + t * 4,
                                                 ga_d + t * 4, gfeat, s_arr, d_arr, n);
    k_edge_l<<<(e + 255) / 256, 256, 0, stream>>>(src_csr, dst_csr, edots + (size_t)t * e,
                                                  s_arr, d_arr, lcsr, e);
    k_agg4<<<(n + 255) / 256, 256, 0, stream>>>(off, src_csr, lcsr, gfeat, gb + t * 4,
                                                gates, n);
  }

  // ---- zero pooled accumulators
  k_zero_f32<<<(nb_graphs * H + 255) / 256, 256, 0, stream>>>(pooled0, nb_graphs * H);
  k_zero_f32<<<(nb_graphs * H + 255) / 256, 256, 0, stream>>>(pooled1, nb_graphs * H);

  // ---- 6 experts (MFMA GEMMs; BN1 fused into layer-2 staging; partial-sum BN stats)
  int gblk = (n + 63) / 64;
  for (int i = 0; i < 6; ++i) {
    // layer 1 (DIN -> H)
    k_mfma_gemm<DIN, false><<<gblk, 256, 0, stream>>>(
        xbf, Wp1 + (size_t)i * 8192, ea_s1 + i * H, ea_d1 + i * H, featbuf, s_arr, d_arr,
        n, nullptr, nullptr, nullptr, 0.f);
    k_edge_l<<<(e + 255) / 256, 256, 0, stream>>>(src_csr, dst_csr,
                                                  edots + (size_t)(2 + i) * e, s_arr,
                                                  d_arr, lcsr, e);
    k_agg128<<<(n + 7) / 8, 256, 0, stream>>>(off, src_csr, lcsr, featbuf, eb1 + i * H,
                                              buf1, n);
    k_bnstats_part<<<NBSTAT, 256, 0, stream>>>(buf1, partials, n);
    k_bnstats_fin<<<16, 256, 0, stream>>>(partials, sums, NBSTAT);
    // layer 2 (H -> H); BN1 + leaky applied during A staging
    k_mfma_gemm<H, true><<<gblk, 256, 0, stream>>>(
        buf1, Wp2 + (size_t)i * 16384, ea_s2 + i * H, ea_d2 + i * H, featbuf, s_arr,
        d_arr, n, sums, bn1_g + i * H, bn1_b + i * H, invn);
    k_edge_l<<<(e + 255) / 256, 256, 0, stream>>>(src_csr, dst_csr,
                                                  edots + (size_t)(8 + i) * e, s_arr,
                                                  d_arr, lcsr, e);
    k_agg128<<<(n + 7) / 8, 256, 0, stream>>>(off, src_csr, lcsr, featbuf, eb2 + i * H,
                                              buf1, n);
    k_bnstats_part<<<NBSTAT, 256, 0, stream>>>(buf1, partials, n);
    k_bnstats_fin<<<16, 256, 0, stream>>>(partials, sums, NBSTAT);
    int s0 = (i < 4) ? i : -1;
    int s1 = (i < 2) ? i : (i >= 4 ? i - 2 : -1);
    k_poolexpert<<<nb_graphs, 64, 0, stream>>>(buf1, sums, sums + 128, bn2_g + i * H,
                                               bn2_b + i * H, batch, gates0, s0, gates1,
                                               s1, pooled0, pooled1, n, invn);
  }

  // ---- heads
  for (int t = 0; t < 2; ++t) {
    const float* pooled = t ? pooled1 : pooled0;
    k_kv<<<L, 128, 0, stream>>>(pe + (size_t)t * L * PD, Wk + t * PD * H, Wv + t * PD * H,
                                Ktbuf, Vbuf);
    k_rowgemm<<<nb_graphs, 128, 0, stream>>>(pooled, Wq + t * H * H, Qbuf, H);
    k_attn<<<nb_graphs / 4, 128, 0, stream>>>(Qbuf, Ktbuf, Vbuf, ctxb);
    k_head1<<<nb_graphs, 128, 0, stream>>>(pooled, ctxb, Wh1 + t * 2 * H * H, bh1 + t * H,
                                           hhb);
    k_zero_f32<<<1, 256, 0, stream>>>(sums, 256);
    k_bnstats_f32<<<64, 256, 0, stream>>>(hhb, sums, sums + 128, nb_graphs);
    k_head2<<<nb_graphs, 128, 0, stream>>>(hhb, sums, sums + 128, hbn_g + t * H,
                                           hbn_b + t * H, Wh2 + t * H, bh2 + t, out, t,
                                           1.0f / nb_graphs);
  }
}